// Round 8
// baseline (2550.128 us; speedup 1.0000x reference)
//
#include <hip/hip_runtime.h>
#include <cstdint>
#include <cstddef>

#define B_    256
#define Q_    512
#define D_    32
#define H_    192
#define HID_  384
#define INCH_ 96
#define M_    (B_*Q_)    // 131072
#define WOUT_ 64
#define BPB   2          // batches per rollout block
#define RT_   768        // rollout threads: 4 quarters x 192, 12 waves
#define PI_F  3.14159265358979323846f

typedef unsigned int uint_t;

__device__ __forceinline__ float sigm(float x){ return 1.f/(1.f+expf(-x)); }
__device__ __forceinline__ float gelu_exact(float x){ return 0.5f*x*(1.f+erff(x*0.7071067811865475f)); }
__device__ __forceinline__ float4 f4sub(float4 a, float4 b){
  return make_float4(a.x-b.x, a.y-b.y, a.z-b.z, a.w-b.w);
}

// ---------------- on-the-fly features: [x, dy, ddy] column chunk (bit-identical to feats_kernel) ----------------
__device__ __forceinline__ float4 feats_load(const float* __restrict__ x, int bt, int c){
  const int t = bt & 511;
  const int seg = c >> 5, d = c & 31;
  const float* xr = x + (size_t)bt*D_ + d;
  float4 x0 = *(const float4*)xr;
  if (seg == 0) return x0;
  if (t == 0) return make_float4(0.f,0.f,0.f,0.f);
  float4 x1 = *(const float4*)(xr - D_);
  float4 dy = f4sub(x0, x1);
  if (seg == 1) return dy;
  if (t == 1) return dy;                 // dym1 = 0 -> ddy = dy
  float4 x2 = *(const float4*)(xr - 2*D_);
  float4 dym1 = f4sub(x1, x2);
  return f4sub(dy, dym1);
}

// ---------------- 128x192x16 fp32 GEMM, acc[8][12], 2 blocks/CU (VGPR cap 256: spill-proof) ----------------
// MODE 1: out = gelu(acc+bias), + per-block GRN column sum-of-squares partials -> gpart
// MODE 2: A affine (scale/grnb), C += acc+bias
// Per-output k-order is k-ascending (identical to the 128x64 version -> bit-identical results).
// GRN partial sum order: i=0..7 within ty-block, then ty=0..15 -> identical to old red[][] order.
template<int MODE>
__global__ __launch_bounds__(256,2) void gemm_w192(
    const float* __restrict__ Af,
    const float* __restrict__ W,  const float* __restrict__ bias,
    float* __restrict__ Cf,
    const float* __restrict__ scale, const float* __restrict__ grnb,
    float* __restrict__ gpart,
    int N, int K)
{
  __shared__ float smem[16*128 + 16*192];   // As[16][128] then Bs[16][192]; red[16][192] reuses
  float* AsB = smem;
  float* BsB = smem + 16*128;
  const int tid = threadIdx.x;
  const int bm = blockIdx.x*128, bn = blockIdx.y*192;
  const int tx = tid & 15, ty = tid >> 4;
  const int arow = tid >> 1, ak = (tid & 1)*4;   // A: 128 rows x 2 threads, 2 chunks each
  const int br = tid >> 2,  bk = (tid & 3)*4;    // B: rows br, br+64, br+128 ; 4 threads/row
  const float* srow = (MODE==2) ? (scale + (size_t)(bm>>9)*HID_) : nullptr;

  float acc[8][12];
  #pragma unroll
  for (int i=0;i<8;i++)
    #pragma unroll
    for (int j=0;j<12;j++) acc[i][j]=0.f;

  const float* gA  = Af + (size_t)(bm+arow)*K;
  const float* gB0 = W  + (size_t)(bn+br)*K;
  const float* gB1 = W  + (size_t)(bn+br+64)*K;
  const float* gB2 = W  + (size_t)(bn+br+128)*K;

  for (int k0=0;k0<K;k0+=16){
    float4 va0 = *(const float4*)(gA + k0 + ak);
    float4 va1 = *(const float4*)(gA + k0 + ak + 8);
    float4 vb0 = *(const float4*)(gB0 + k0 + bk);
    float4 vb1 = *(const float4*)(gB1 + k0 + bk);
    float4 vb2 = *(const float4*)(gB2 + k0 + bk);
    if (MODE==2){
      int c0 = k0+ak, c1 = k0+ak+8;
      float4 s0 = *(const float4*)(srow+c0);
      float4 g0 = *(const float4*)(grnb+c0);
      float4 s1 = *(const float4*)(srow+c1);
      float4 g1 = *(const float4*)(grnb+c1);
      va0.x = va0.x*s0.x+g0.x; va0.y = va0.y*s0.y+g0.y;
      va0.z = va0.z*s0.z+g0.z; va0.w = va0.w*s0.w+g0.w;
      va1.x = va1.x*s1.x+g1.x; va1.y = va1.y*s1.y+g1.y;
      va1.z = va1.z*s1.z+g1.z; va1.w = va1.w*s1.w+g1.w;
    }
    AsB[(ak+0)*128+arow]=va0.x; AsB[(ak+1)*128+arow]=va0.y; AsB[(ak+2)*128+arow]=va0.z; AsB[(ak+3)*128+arow]=va0.w;
    AsB[(ak+8)*128+arow]=va1.x; AsB[(ak+9)*128+arow]=va1.y; AsB[(ak+10)*128+arow]=va1.z; AsB[(ak+11)*128+arow]=va1.w;
    BsB[(bk+0)*192+br]=vb0.x; BsB[(bk+1)*192+br]=vb0.y; BsB[(bk+2)*192+br]=vb0.z; BsB[(bk+3)*192+br]=vb0.w;
    BsB[(bk+0)*192+br+64]=vb1.x; BsB[(bk+1)*192+br+64]=vb1.y; BsB[(bk+2)*192+br+64]=vb1.z; BsB[(bk+3)*192+br+64]=vb1.w;
    BsB[(bk+0)*192+br+128]=vb2.x; BsB[(bk+1)*192+br+128]=vb2.y; BsB[(bk+2)*192+br+128]=vb2.z; BsB[(bk+3)*192+br+128]=vb2.w;
    __syncthreads();
    #pragma unroll
    for (int kk=0;kk<16;kk++){
      float4 a0 = *(const float4*)&AsB[kk*128 + ty*8];
      float4 a1 = *(const float4*)&AsB[kk*128 + ty*8 + 4];
      float4 b0 = *(const float4*)&BsB[kk*192 + tx*12];
      float4 b1 = *(const float4*)&BsB[kk*192 + tx*12 + 4];
      float4 b2 = *(const float4*)&BsB[kk*192 + tx*12 + 8];
      float ar[8] = {a0.x,a0.y,a0.z,a0.w,a1.x,a1.y,a1.z,a1.w};
      #pragma unroll
      for (int i=0;i<8;i++){
        acc[i][0] += ar[i]*b0.x; acc[i][1] += ar[i]*b0.y; acc[i][2] += ar[i]*b0.z; acc[i][3] += ar[i]*b0.w;
        acc[i][4] += ar[i]*b1.x; acc[i][5] += ar[i]*b1.y; acc[i][6] += ar[i]*b1.z; acc[i][7] += ar[i]*b1.w;
        acc[i][8] += ar[i]*b2.x; acc[i][9] += ar[i]*b2.y; acc[i][10]+= ar[i]*b2.z; acc[i][11]+= ar[i]*b2.w;
      }
    }
    __syncthreads();
  }

  const int o0 = bn + tx*12;
  float4 bb0 = *(const float4*)(bias + o0);
  float4 bb1 = *(const float4*)(bias + o0 + 4);
  float4 bb2 = *(const float4*)(bias + o0 + 8);
  float q[12];
  #pragma unroll
  for (int j=0;j<12;j++) q[j]=0.f;

  #pragma unroll
  for (int i=0;i<8;i++){
    int m = bm + ty*8 + i;
    float* crow = Cf + (size_t)m*N + o0;
    if (MODE==1){
      float4 v0, v1, v2;
      v0.x = gelu_exact(acc[i][0]+bb0.x); v0.y = gelu_exact(acc[i][1]+bb0.y);
      v0.z = gelu_exact(acc[i][2]+bb0.z); v0.w = gelu_exact(acc[i][3]+bb0.w);
      v1.x = gelu_exact(acc[i][4]+bb1.x); v1.y = gelu_exact(acc[i][5]+bb1.y);
      v1.z = gelu_exact(acc[i][6]+bb1.z); v1.w = gelu_exact(acc[i][7]+bb1.w);
      v2.x = gelu_exact(acc[i][8]+bb2.x); v2.y = gelu_exact(acc[i][9]+bb2.y);
      v2.z = gelu_exact(acc[i][10]+bb2.z); v2.w = gelu_exact(acc[i][11]+bb2.w);
      *(float4*)(crow+0) = v0; *(float4*)(crow+4) = v1; *(float4*)(crow+8) = v2;
      q[0]+=v0.x*v0.x; q[1]+=v0.y*v0.y; q[2]+=v0.z*v0.z; q[3]+=v0.w*v0.w;
      q[4]+=v1.x*v1.x; q[5]+=v1.y*v1.y; q[6]+=v1.z*v1.z; q[7]+=v1.w*v1.w;
      q[8]+=v2.x*v2.x; q[9]+=v2.y*v2.y; q[10]+=v2.z*v2.z; q[11]+=v2.w*v2.w;
    } else {
      float4 o0v = *(const float4*)(crow+0);
      float4 o1v = *(const float4*)(crow+4);
      float4 o2v = *(const float4*)(crow+8);
      float4 v0, v1, v2;
      v0.x=o0v.x+acc[i][0]+bb0.x; v0.y=o0v.y+acc[i][1]+bb0.y;
      v0.z=o0v.z+acc[i][2]+bb0.z; v0.w=o0v.w+acc[i][3]+bb0.w;
      v1.x=o1v.x+acc[i][4]+bb1.x; v1.y=o1v.y+acc[i][5]+bb1.y;
      v1.z=o1v.z+acc[i][6]+bb1.z; v1.w=o1v.w+acc[i][7]+bb1.w;
      v2.x=o2v.x+acc[i][8]+bb2.x; v2.y=o2v.y+acc[i][9]+bb2.y;
      v2.z=o2v.z+acc[i][10]+bb2.z; v2.w=o2v.w+acc[i][11]+bb2.w;
      *(float4*)(crow+0) = v0; *(float4*)(crow+4) = v1; *(float4*)(crow+8) = v2;
    }
  }

  if (MODE==1){
    // reuse smem as red[16][192] (all As/Bs reads completed; trailing barrier above)
    #pragma unroll
    for (int j=0;j<12;j++) smem[ty*192 + tx*12 + j] = q[j];
    __syncthreads();
    if (tid < 192){
      float s = 0.f;
      #pragma unroll
      for (int t=0;t<16;t++) s += smem[t*192 + tid];
      const int slot = (bm>>7)&3, b = bm>>9;
      gpart[((size_t)(b*4+slot))*HID_ + bn + tid] = s;
    }
  }
}

// ---------------- input GEMM: fused feature synthesis, 128x192 tile (N=192, K=96) ----------------
__global__ __launch_bounds__(256,2) void gemm_inp_w192(
    const float* __restrict__ x,
    const float* __restrict__ W,  const float* __restrict__ bias,
    float* __restrict__ Cf)
{
  __shared__ float smem[16*128 + 16*192];
  float* AsB = smem;
  float* BsB = smem + 16*128;
  const int tid = threadIdx.x;
  const int bm = blockIdx.x*128;
  const int tx = tid & 15, ty = tid >> 4;
  const int arow = tid >> 1, ak = (tid & 1)*4;
  const int br = tid >> 2,  bk = (tid & 3)*4;
  const int K = INCH_, N = H_;

  float acc[8][12];
  #pragma unroll
  for (int i=0;i<8;i++)
    #pragma unroll
    for (int j=0;j<12;j++) acc[i][j]=0.f;

  const float* gB0 = W + (size_t)(br)*K;
  const float* gB1 = W + (size_t)(br+64)*K;
  const float* gB2 = W + (size_t)(br+128)*K;

  for (int k0=0;k0<K;k0+=16){
    float4 va0 = feats_load(x, bm+arow, k0+ak);
    float4 va1 = feats_load(x, bm+arow, k0+ak+8);
    float4 vb0 = *(const float4*)(gB0 + k0 + bk);
    float4 vb1 = *(const float4*)(gB1 + k0 + bk);
    float4 vb2 = *(const float4*)(gB2 + k0 + bk);
    AsB[(ak+0)*128+arow]=va0.x; AsB[(ak+1)*128+arow]=va0.y; AsB[(ak+2)*128+arow]=va0.z; AsB[(ak+3)*128+arow]=va0.w;
    AsB[(ak+8)*128+arow]=va1.x; AsB[(ak+9)*128+arow]=va1.y; AsB[(ak+10)*128+arow]=va1.z; AsB[(ak+11)*128+arow]=va1.w;
    BsB[(bk+0)*192+br]=vb0.x; BsB[(bk+1)*192+br]=vb0.y; BsB[(bk+2)*192+br]=vb0.z; BsB[(bk+3)*192+br]=vb0.w;
    BsB[(bk+0)*192+br+64]=vb1.x; BsB[(bk+1)*192+br+64]=vb1.y; BsB[(bk+2)*192+br+64]=vb1.z; BsB[(bk+3)*192+br+64]=vb1.w;
    BsB[(bk+0)*192+br+128]=vb2.x; BsB[(bk+1)*192+br+128]=vb2.y; BsB[(bk+2)*192+br+128]=vb2.z; BsB[(bk+3)*192+br+128]=vb2.w;
    __syncthreads();
    #pragma unroll
    for (int kk=0;kk<16;kk++){
      float4 a0 = *(const float4*)&AsB[kk*128 + ty*8];
      float4 a1 = *(const float4*)&AsB[kk*128 + ty*8 + 4];
      float4 b0 = *(const float4*)&BsB[kk*192 + tx*12];
      float4 b1 = *(const float4*)&BsB[kk*192 + tx*12 + 4];
      float4 b2 = *(const float4*)&BsB[kk*192 + tx*12 + 8];
      float ar[8] = {a0.x,a0.y,a0.z,a0.w,a1.x,a1.y,a1.z,a1.w};
      #pragma unroll
      for (int i=0;i<8;i++){
        acc[i][0] += ar[i]*b0.x; acc[i][1] += ar[i]*b0.y; acc[i][2] += ar[i]*b0.z; acc[i][3] += ar[i]*b0.w;
        acc[i][4] += ar[i]*b1.x; acc[i][5] += ar[i]*b1.y; acc[i][6] += ar[i]*b1.z; acc[i][7] += ar[i]*b1.w;
        acc[i][8] += ar[i]*b2.x; acc[i][9] += ar[i]*b2.y; acc[i][10]+= ar[i]*b2.z; acc[i][11]+= ar[i]*b2.w;
      }
    }
    __syncthreads();
  }

  const int o0 = tx*12;
  float4 bb0 = *(const float4*)(bias + o0);
  float4 bb1 = *(const float4*)(bias + o0 + 4);
  float4 bb2 = *(const float4*)(bias + o0 + 8);
  #pragma unroll
  for (int i=0;i<8;i++){
    int m = bm + ty*8 + i;
    float* crow = Cf + (size_t)m*N + o0;
    float4 v0, v1, v2;
    v0.x=acc[i][0]+bb0.x; v0.y=acc[i][1]+bb0.y; v0.z=acc[i][2]+bb0.z; v0.w=acc[i][3]+bb0.w;
    v1.x=acc[i][4]+bb1.x; v1.y=acc[i][5]+bb1.y; v1.z=acc[i][6]+bb1.z; v1.w=acc[i][7]+bb1.w;
    v2.x=acc[i][8]+bb2.x; v2.y=acc[i][9]+bb2.y; v2.z=acc[i][10]+bb2.z; v2.w=acc[i][11]+bb2.w;
    *(float4*)(crow+0) = v0; *(float4*)(crow+4) = v1; *(float4*)(crow+8) = v2;
  }
}

// ---------------- 128x64x16 fp32 GEMM (kept only for MODE 3: Kalman projection, N=64) ----------------
template<int MODE>
__global__ __launch_bounds__(256,4) void gemm_t128(
    const float* __restrict__ Af,
    const float* __restrict__ W,  const float* __restrict__ bias,
    float* __restrict__ Cf,
    const float* __restrict__ scale, const float* __restrict__ grnb,
    float* __restrict__ gpart,
    int N, int K)
{
  __shared__ float As[16][128];
  __shared__ float Bs[16][64];
  const int tid = threadIdx.x;
  const int bm = blockIdx.x*128, bn = blockIdx.y*64;
  const int tx = tid & 15, ty = tid >> 4;
  const int arow = tid >> 1, ak = (tid & 1)*4;
  const int brow = tid >> 2, bk = (tid & 3)*4;

  float acc[8][4];
  #pragma unroll
  for (int i=0;i<8;i++)
    #pragma unroll
    for (int j=0;j<4;j++) acc[i][j]=0.f;

  const float* gA = Af + (size_t)(bm+arow)*K;
  const float* gB = W  + (size_t)(bn+brow)*K;

  for (int k0=0;k0<K;k0+=16){
    float4 va0 = *(const float4*)(gA + k0 + ak);
    float4 va1 = *(const float4*)(gA + k0 + ak + 8);
    float4 vb  = *(const float4*)(gB + k0 + bk);
    As[ak+0][arow]=va0.x; As[ak+1][arow]=va0.y; As[ak+2][arow]=va0.z; As[ak+3][arow]=va0.w;
    As[ak+8][arow]=va1.x; As[ak+9][arow]=va1.y; As[ak+10][arow]=va1.z; As[ak+11][arow]=va1.w;
    Bs[bk+0][brow]=vb.x; Bs[bk+1][brow]=vb.y; Bs[bk+2][brow]=vb.z; Bs[bk+3][brow]=vb.w;
    __syncthreads();
    #pragma unroll
    for (int kk=0;kk<16;kk++){
      float4 a0 = *(const float4*)&As[kk][ty*8];
      float4 a1 = *(const float4*)&As[kk][ty*8+4];
      float4 b  = *(const float4*)&Bs[kk][tx*4];
      float ar[8] = {a0.x,a0.y,a0.z,a0.w,a1.x,a1.y,a1.z,a1.w};
      #pragma unroll
      for (int i=0;i<8;i++){
        acc[i][0] += ar[i]*b.x; acc[i][1] += ar[i]*b.y;
        acc[i][2] += ar[i]*b.z; acc[i][3] += ar[i]*b.w;
      }
    }
    __syncthreads();
  }

  const int o0 = bn + tx*4;
  float4 b0 = *(const float4*)(bias + o0);

  if (MODE==3){
    #pragma unroll
    for (int i=0;i<8;i++){
      int m = bm + ty*8 + i;
      float* ob = Cf + (size_t)m*34;
      float vx = acc[i][0]+b0.x, vy = acc[i][1]+b0.y;
      float vz = acc[i][2]+b0.z, vw = acc[i][3]+b0.w;
      if (o0 == 0){
        float rho = 1.25f*sigm(vx);
        float phi = PI_F*tanhf(vy);
        ob[0] = rho*cosf(phi); ob[1] = rho*sinf(phi);
        ob[2] = sigm(vz); ob[3] = sigm(vw);
      } else if (o0 <= 28){
        ob[o0+0]=sigm(vx); ob[o0+1]=sigm(vy); ob[o0+2]=sigm(vz); ob[o0+3]=sigm(vw);
      } else if (o0 == 32){
        ob[32]=sigm(vx); ob[33]=sigm(vy);
      }
    }
    return;
  }
  (void)gpart; (void)scale; (void)grnb;
}

// ---------------- depthwise conv (k=9, edge pad) + wave-local LN: 4 waves, 16 timesteps, 1 barrier ----------------
__global__ __launch_bounds__(256) void dwconv_ln_wave(
  const float* __restrict__ h, const float* __restrict__ dww, const float* __restrict__ dwb,
  const float* __restrict__ lnw, const float* __restrict__ lnb, float* __restrict__ yln)
{
  __shared__ float sh[24][192];
  const int tid  = threadIdx.x;
  const int lane = tid & 63;
  const int wv   = tid >> 6;
  const int t0 = (blockIdx.x & 31) * 16;
  const size_t base = (size_t)(blockIdx.x >> 5) * Q_ * H_;
  #pragma unroll
  for (int i = tid; i < 24*192; i += 256){
    int r = i / 192, c = i - r*192;
    int tt = t0 - 4 + r; tt = tt<0?0:(tt>511?511:tt);
    sh[r][c] = h[base + (size_t)tt*H_ + c];
  }
  const int c0 = lane, c1 = lane+64, c2 = lane+128;
  float w0[9], w1[9], w2[9];
  #pragma unroll
  for (int k=0;k<9;k++){ w0[k]=dww[c0*9+k]; w1[k]=dww[c1*9+k]; w2[k]=dww[c2*9+k]; }
  const float db0=dwb[c0], db1=dwb[c1], db2=dwb[c2];
  const float lw0=lnw[c0], lw1=lnw[c1], lw2=lnw[c2];
  const float lb0=lnb[c0], lb1=lnb[c1], lb2=lnb[c2];
  __syncthreads();
  for (int it=0; it<4; it++){
    const int i = it*4 + wv;
    float a0=db0, a1=db1, a2=db2;
    #pragma unroll
    for (int k=0;k<9;k++){
      a0 += w0[k]*sh[i+k][c0];
      a1 += w1[k]*sh[i+k][c1];
      a2 += w2[k]*sh[i+k][c2];
    }
    float s = a0+a1+a2;
    float qq = a0*a0 + a1*a1 + a2*a2;
    #pragma unroll
    for (int off=32; off>0; off>>=1){ s += __shfl_down(s,off); qq += __shfl_down(qq,off); }
    s = __shfl(s, 0); qq = __shfl(qq, 0);
    float mean = s*(1.f/H_);
    float var  = qq*(1.f/H_) - mean*mean;
    float r = rsqrtf(var + 1e-5f);
    float* ob = yln + base + (size_t)(t0+i)*H_;
    ob[c0] = (a0-mean)*r*lw0 + lb0;
    ob[c1] = (a1-mean)*r*lw1 + lb1;
    ob[c2] = (a2-mean)*r*lw2 + lb2;
  }
}

// ---------------- output LayerNorm, wave-local (4 rows/block, no LDS, no barriers) ----------------
__global__ __launch_bounds__(256) void out_ln_wave(
  const float* __restrict__ h, const float* __restrict__ lnw, const float* __restrict__ lnb,
  float* __restrict__ o, float* __restrict__ hlast, int b0)
{
  const int tid  = threadIdx.x;
  const int lane = tid & 63;
  const int wv   = tid >> 6;
  const int bt = blockIdx.x*4 + wv;
  const float* hr = h + (size_t)bt*H_;
  float v0 = hr[lane], v1 = hr[lane+64], v2 = hr[lane+128];
  float s = v0+v1+v2;
  float qq = v0*v0 + v1*v1 + v2*v2;
  #pragma unroll
  for (int off=32; off>0; off>>=1){ s += __shfl_down(s,off); qq += __shfl_down(qq,off); }
  s = __shfl(s, 0); qq = __shfl(qq, 0);
  float mean = s*(1.f/H_);
  float var  = qq*(1.f/H_) - mean*mean;
  float r = rsqrtf(var + 1e-5f);
  const float r0 = (v0-mean)*r*lnw[lane]     + lnb[lane];
  const float r1 = (v1-mean)*r*lnw[lane+64]  + lnb[lane+64];
  const float r2 = (v2-mean)*r*lnw[lane+128] + lnb[lane+128];
  float* orow = o + (size_t)bt*H_;
  orow[lane] = r0; orow[lane+64] = r1; orow[lane+128] = r2;
  if ((bt & 511) == 511){
    float* hl = hlast + (size_t)(b0 + (bt>>9))*H_;
    hl[lane] = r0; hl[lane+64] = r1; hl[lane+128] = r2;
  }
}

// ---------------- GRN combine: 4 slot partials -> scale ----------------
__global__ __launch_bounds__(384) void grn_combine_kernel(
  const float* __restrict__ gpart, const float* __restrict__ grn_g, float* __restrict__ scale)
{
  __shared__ float r[384];
  const int c = threadIdx.x;
  const int b = blockIdx.x;
  const float* p = gpart + (size_t)b*4*HID_;
  float s = ((p[c] + p[HID_+c]) + p[2*HID_+c]) + p[3*HID_+c];
  float gx = sqrtf(s);
  r[c] = gx;
  __syncthreads();
  if (c < 64){
    float v = r[c]+r[c+64]+r[c+128]+r[c+192]+r[c+256]+r[c+320];
    #pragma unroll
    for (int off=32; off>0; off>>=1) v += __shfl_down(v,off);
    if (c==0) r[0]=v;
  }
  __syncthreads();
  float mean = r[0]*(1.f/HID_);
  scale[(size_t)b*HID_ + c] = 1.f + grn_g[c]*gx/(mean + 1e-6f);
}

// ---------------- pack fc_rp / fc_gain into padded (64,192) W ----------------
__global__ void pack_w_kernel(const float* __restrict__ frw, const float* __restrict__ frb,
                              const float* __restrict__ fgw, const float* __restrict__ fgb,
                              float* __restrict__ w_pad, float* __restrict__ b_pad)
{
  int idx = blockIdx.x*256 + threadIdx.x;
  if (idx >= 64*192) return;
  int o = idx / 192, k = idx % 192;
  float v = 0.f;
  if (o < 2) v = frw[o*192+k]; else if (o < 34) v = fgw[(o-2)*192+k];
  w_pad[idx] = v;
  if (k == 0){
    float bv = 0.f;
    if (o < 2) bv = frb[o]; else if (o < 34) bv = fgb[o-2];
    b_pad[o] = bv;
  }
}

// ---------------- sequential Kalman scan (FMA-only) ----------------
__global__ __launch_bounds__(64) void kalman_scan_kernel(
  const float* __restrict__ x_c, const float* __restrict__ rp, float* __restrict__ xpost,
  int b0, int Bc)
{
  const int lane = threadIdx.x;
  const int bl = blockIdx.x*4 + (lane>>4);
  if (bl >= Bc) return;
  const int m = lane & 15;
  const float* xb  = x_c + (size_t)bl*Q_*D_;
  const float* rpb = rp  + (size_t)bl*Q_*34;
  float re = xb[m], im = xb[16+m];
  for (int t=0;t<Q_;t++){
    const float* r = rpb + (size_t)t*34;
    float rc = r[0], rs = r[1];
    float g0 = r[2+m], g1 = r[18+m];
    float y0 = xb[(size_t)t*D_ + m], y1v = xb[(size_t)t*D_ + 16 + m];
    float pr  = rc*re - rs*im;
    float pim = rs*re + rc*im;
    re = pr  + g0*(y0  - pr);
    im = pim + g1*(y1v - pim);
  }
  xpost[(b0+bl)*D_ + m] = re;
  xpost[(b0+bl)*D_ + 16 + m] = im;
}

// ---------------- rollout weight prep: wT1[k][o] + packed [k][o][8] gate block ----------------
__global__ void prep_rollout_kernel(const float* __restrict__ riw, const float* __restrict__ wih,
                                    const float* __restrict__ whh,
                                    float* __restrict__ wT1, float* __restrict__ wPack)
{
  int idx = blockIdx.x*256 + threadIdx.x;
  if (idx < 224*192){
    int o = idx % 192, k = idx / 192;
    wT1[idx] = riw[o*224 + k];
    return;
  }
  idx -= 224*192;
  if (idx < 192*192){
    int o = idx % 192, k = idx / 192;
    float* w = wPack + ((size_t)k*192 + o)*8;
    w[0] = wih[(0*192+o)*192 + k];
    w[1] = wih[(1*192+o)*192 + k];
    w[2] = wih[(2*192+o)*192 + k];
    w[3] = whh[(0*192+o)*192 + k];
    w[4] = whh[(1*192+o)*192 + k];
    w[5] = whh[(2*192+o)*192 + k];
    w[6] = 0.f; w[7] = 0.f;
  }
}

// ---------------- GRU rollout v3 (proven 890us): BPB=2, 128 blocks ----------------
// - wT1 (phase-A weights) live in 56 registers per thread, loaded once (step-invariant).
//   NOTE: phase-B weights stay as L2 streams; promoting them (288 floats) exceeds SROA's
//   limit and spills to scratch (R3: 3.5 GB scratch traffic, 2.3 ms). Do not retry.
// - Single fused reduction per step; LN-update and Kalman-rotate run concurrently.
__global__ __launch_bounds__(RT_,3) void rollout_kernel(
  const float* __restrict__ hlast, const float* __restrict__ xpost,
  const float* __restrict__ wT1,  const float* __restrict__ rib_,
  const float* __restrict__ wPack,
  const float* __restrict__ bih,  const float* __restrict__ bhh,
  const float* __restrict__ lnw,  const float* __restrict__ lnb,
  const float* __restrict__ frw,  const float* __restrict__ frb,
  float* __restrict__ out)
{
  const int tid = threadIdx.x;
  const int q   = tid / 192;        // quarter 0..3 (wave-aligned: 192 = 3 waves)
  const int o   = tid - q*192;      // channel 0..191
  const int bb  = blockIdx.x*BPB;

  __shared__ float hT[192][2];      // h state, batch-major
  __shared__ float xT[192][2];      // x = tanh(W1 [h;c]), batch-major
  __shared__ float cT[32][2];       // curr (Kalman state), batch-major
  __shared__ float pA[4][2][192];   // phase-A partials [quarter][batch][o]
  __shared__ float pB[4][12][192];  // phase-B partials [quarter][batch*6+gate][o]
  __shared__ float rsum[2][3][4];   // [batch][wave][S1,S2,S3,S4]

  // ---- init state ----
  if (q < 2){
    hT[o][q] = hlast[(size_t)(bb+q)*H_ + o];
    if (o < 32) cT[o][q] = xpost[(bb+q)*D_ + o];
  }

  const float w_ln = lnw[o], b_ln = lnb[o];
  const float fr0  = frw[o], fr1  = frw[192+o];
  const float fb0 = frb[0],  fb1 = frb[1];
  const float bi0 = bih[o], bi1 = bih[192+o], bi2 = bih[384+o];
  const float bh0 = bhh[o], bh1 = bhh[192+o], bh2 = bhh[384+o];
  const float rib = rib_[o];
  const float u0 = w_ln*fr0, u1 = w_ln*fr1;      // for fused projection
  const float t0c = b_ln*fr0, t1c = b_ln*fr1;

  // ---- phase-A weights in registers (step-invariant) ----
  float wreg[56];
  if (q < 3){
    const int kb = 56*q;
    #pragma unroll
    for (int i=0;i<56;i++) wreg[i] = wT1[(kb+i)*192+o];
  } else {
    #pragma unroll
    for (int i=0;i<24;i++) wreg[i] = wT1[(168+i)*192+o];
    #pragma unroll
    for (int i=0;i<32;i++) wreg[24+i] = wT1[(192+i)*192+o];
  }

  // ---- one-time constants: C0=sum(u0), C1=sum(u1), K0=sum(lnb*fr0)+fb0, K1=sum(lnb*fr1)+fb1 ----
  {
    float c0=u0, c1=u1, k0=t0c, k1=t1c;
    #pragma unroll
    for (int off=32; off>0; off>>=1){
      c0 += __shfl_down(c0,off); c1 += __shfl_down(c1,off);
      k0 += __shfl_down(k0,off); k1 += __shfl_down(k1,off);
    }
    if (q==0 && (o&63)==0){
      int w = o>>6;
      rsum[0][w][0]=c0; rsum[0][w][1]=c1; rsum[0][w][2]=k0; rsum[0][w][3]=k1;
    }
  }
  __syncthreads();
  const float C0 = rsum[0][0][0]+rsum[0][1][0]+rsum[0][2][0];
  const float C1 = rsum[0][0][1]+rsum[0][1][1]+rsum[0][2][1];
  const float K0 = rsum[0][0][2]+rsum[0][1][2]+rsum[0][2][2] + fb0;
  const float K1 = rsum[0][0][3]+rsum[0][1][3]+rsum[0][2][3] + fb1;

  for (int s=0; s<WOUT_; s++){
    // ---- phase A: partial x = W1 @ [h;c], K=224 split 4-way, weights in regs ----
    float a0=0.f, a1=0.f;
    if (q < 3){
      const int kb = 56*q;
      #pragma unroll
      for (int i=0;i<56;i++){
        float2 h2 = *(const float2*)&hT[kb+i][0];
        a0 += wreg[i]*h2.x; a1 += wreg[i]*h2.y;
      }
    } else {
      #pragma unroll
      for (int i=0;i<24;i++){
        float2 h2 = *(const float2*)&hT[168+i][0];
        a0 += wreg[i]*h2.x; a1 += wreg[i]*h2.y;
      }
      #pragma unroll
      for (int i=0;i<32;i++){
        float2 c2 = *(const float2*)&cT[i][0];
        a0 += wreg[24+i]*c2.x; a1 += wreg[24+i]*c2.y;
      }
    }
    pA[q][0][o]=a0; pA[q][1][o]=a1;
    __syncthreads();

    // ---- x combine: quarter j (<2) owns batch j ----
    if (q < 2){
      xT[o][q] = tanhf(rib + pA[0][q][o] + pA[1][q][o] + pA[2][q][o] + pA[3][q][o]);
    }
    __syncthreads();

    // ---- phase B: partial gates, K=192 split 4-way (48 each) ----
    float accx[2][3] = {{0.f,0.f,0.f},{0.f,0.f,0.f}};
    float acch[2][3] = {{0.f,0.f,0.f},{0.f,0.f,0.f}};
    {
      const int kb2 = 48*q;
      #pragma unroll 4
      for (int i=0;i<48;i++){
        const int k = kb2+i;
        const float4* wp = (const float4*)(wPack + ((size_t)k*192 + o)*8);
        const float4 wA = wp[0];
        const float4 wB = wp[1];
        const float2 xx = *(const float2*)&xT[k][0];
        const float2 hh = *(const float2*)&hT[k][0];
        accx[0][0] += wA.x*xx.x; accx[0][1] += wA.y*xx.x; accx[0][2] += wA.z*xx.x;
        accx[1][0] += wA.x*xx.y; accx[1][1] += wA.y*xx.y; accx[1][2] += wA.z*xx.y;
        acch[0][0] += wA.w*hh.x; acch[0][1] += wB.x*hh.x; acch[0][2] += wB.y*hh.x;
        acch[1][0] += wA.w*hh.y; acch[1][1] += wB.x*hh.y; acch[1][2] += wB.y*hh.y;
      }
    }
    #pragma unroll
    for (int j=0;j<2;j++){
      #pragma unroll
      for (int g=0;g<3;g++){
        pB[q][j*6+g][o]   = accx[j][g];
        pB[q][j*6+3+g][o] = acch[j][g];
      }
    }
    __syncthreads();

    // ---- gate combine + fused 4-sum wave reduction (quarters 0/1 own batch q) ----
    float pre = 0.f;
    if (q < 2){
      const int g6 = q*6;
      float P0 = bi0 + pB[0][g6+0][o]+pB[1][g6+0][o]+pB[2][g6+0][o]+pB[3][g6+0][o];
      float P1 = bi1 + pB[0][g6+1][o]+pB[1][g6+1][o]+pB[2][g6+1][o]+pB[3][g6+1][o];
      float P2 = bi2 + pB[0][g6+2][o]+pB[1][g6+2][o]+pB[2][g6+2][o]+pB[3][g6+2][o];
      float Q0 = bh0 + pB[0][g6+3][o]+pB[1][g6+3][o]+pB[2][g6+3][o]+pB[3][g6+3][o];
      float Q1 = bh1 + pB[0][g6+4][o]+pB[1][g6+4][o]+pB[2][g6+4][o]+pB[3][g6+4][o];
      float Q2 = bh2 + pB[0][g6+5][o]+pB[1][g6+5][o]+pB[2][g6+5][o]+pB[3][g6+5][o];
      float rg = sigm(P0+Q0), zz = sigm(P1+Q1);
      float nn = tanhf(P2 + rg*Q2);
      pre = (1.f-zz)*nn + zz*hT[o][q];
      float s1 = pre, s2 = pre*pre, s3 = pre*u0, s4 = pre*u1;
      #pragma unroll
      for (int off=32; off>0; off>>=1){
        s1 += __shfl_down(s1,off); s2 += __shfl_down(s2,off);
        s3 += __shfl_down(s3,off); s4 += __shfl_down(s4,off);
      }
      if ((o&63)==0){
        int w = o>>6;
        rsum[q][w][0]=s1; rsum[q][w][1]=s2; rsum[q][w][2]=s3; rsum[q][w][3]=s4;
      }
    }
    __syncthreads();

    // ---- concurrent tail: LN update (q<2) || Kalman rotate (q>=2, o<16) ----
    if (q < 2){
      float S1 = rsum[q][0][0]+rsum[q][1][0]+rsum[q][2][0];
      float S2 = rsum[q][0][1]+rsum[q][1][1]+rsum[q][2][1];
      float mu  = S1*(1.f/192.f);
      float var = S2*(1.f/192.f) - mu*mu;
      float r = rsqrtf(var+1e-5f);
      hT[o][q] = (pre-mu)*r*w_ln + b_ln;
    } else if (o < 16){
      const int j = q-2;
      float S1 = rsum[j][0][0]+rsum[j][1][0]+rsum[j][2][0];
      float S2 = rsum[j][0][1]+rsum[j][1][1]+rsum[j][2][1];
      float S3 = rsum[j][0][2]+rsum[j][1][2]+rsum[j][2][2];
      float S4 = rsum[j][0][3]+rsum[j][1][3]+rsum[j][2][3];
      float mu  = S1*(1.f/192.f);
      float var = S2*(1.f/192.f) - mu*mu;
      float r = rsqrtf(var+1e-5f);
      float proj0 = r*(S3 - mu*C0) + K0;
      float proj1 = r*(S4 - mu*C1) + K1;
      float rho = 1.25f*sigm(proj0);
      float phi = PI_F*tanhf(proj1);
      float rc = rho*cosf(phi), rs = rho*sinf(phi);
      float re = cT[o][j], im = cT[o+16][j];
      float nre = rc*re - rs*im;
      float nim = rs*re + rc*im;
      cT[o][j] = nre; cT[o+16][j] = nim;
      float* ob = out + ((size_t)(bb+j)*WOUT_ + s)*D_;
      ob[o] = nre; ob[o+16] = nim;
    }
    __syncthreads();
  }
}

// ---------------- host launch ----------------
extern "C" void kernel_launch(void* const* d_in, const int* in_sizes, int n_in,
                              void* d_out, int out_size, void* d_ws, size_t ws_size,
                              hipStream_t stream)
{
  const float* x_in     = (const float*)d_in[0];
  const float* inp_w    = (const float*)d_in[1];
  const float* inp_b    = (const float*)d_in[2];
  const float* b_dw_w   = (const float*)d_in[3];
  const float* b_dw_b   = (const float*)d_in[4];
  const float* b_ln_w   = (const float*)d_in[5];
  const float* b_ln_b   = (const float*)d_in[6];
  const float* b_pw1_w  = (const float*)d_in[7];
  const float* b_pw1_b  = (const float*)d_in[8];
  const float* b_grn_g  = (const float*)d_in[9];
  const float* b_grn_b  = (const float*)d_in[10];
  const float* b_pw2_w  = (const float*)d_in[11];
  const float* b_pw2_b  = (const float*)d_in[12];
  const float* out_ln_w = (const float*)d_in[13];
  const float* out_ln_b = (const float*)d_in[14];
  const float* fc_rp_w  = (const float*)d_in[15];
  const float* fc_rp_b  = (const float*)d_in[16];
  const float* fc_gain_w= (const float*)d_in[17];
  const float* fc_gain_b= (const float*)d_in[18];
  const float* roll_in_w= (const float*)d_in[19];
  const float* roll_in_b= (const float*)d_in[20];
  const float* gru_wih  = (const float*)d_in[21];
  const float* gru_whh  = (const float*)d_in[22];
  const float* gru_bih  = (const float*)d_in[23];
  const float* gru_bhh  = (const float*)d_in[24];
  const float* roll_ln_w= (const float*)d_in[25];
  const float* roll_ln_b= (const float*)d_in[26];
  const float* fc_rp_r_w= (const float*)d_in[27];
  const float* fc_rp_r_b= (const float*)d_in[28];
  float* out = (float*)d_out;

  // ---- adaptive chunking ----
  const size_t SMAL_FLOATS = 899136 + 4096;
  size_t ws_floats = ws_size / 4;
  int nchunk = 256;
  const int cand[9] = {1,2,4,8,16,32,64,128,256};
  for (int ci=0; ci<9; ci++){
    size_t Mc_try = (size_t)M_ / cand[ci];
    if (Mc_try*768 + SMAL_FLOATS <= ws_floats){ nchunk = cand[ci]; break; }
  }
  const int    Bc = B_ / nchunk;
  const size_t Mc = (size_t)Bc * Q_;

  float* ws    = (float*)d_ws;
  float* h_c   = ws;
  float* yln_c = h_c   + Mc*192;
  float* mid_c = yln_c + Mc*192;
  float* smal  = mid_c + Mc*384;

  float* y1_c    = mid_c;
  float* rp_c    = mid_c;                // Mc*34 (y1 dead by then)

  float* scaleB = smal;                  // Bc*384 (reserve 98304)
  float* w_pad  = smal + 98304;          // 64*192
  float* b_pad  = w_pad + 12288;         // 64
  float* xpost  = b_pad + 64;            // B_*32
  float* hlast  = xpost + 8192;          // B_*192
  float* wT1    = hlast + 49152;         // 224*192
  float* wPack  = wT1 + 43008;           // 192*192*8
  float* gpart  = wPack + 294912;        // 4*Bc*384 (reserve 393216)

  // one-time weight prep
  pack_w_kernel<<<(64*192+255)/256, 256, 0, stream>>>(fc_rp_w, fc_rp_b, fc_gain_w, fc_gain_b, w_pad, b_pad);
  prep_rollout_kernel<<<(224*192+192*192+255)/256, 256, 0, stream>>>(roll_in_w, gru_wih, gru_whh, wT1, wPack);

  const int gmx = (int)(Mc/128);
  for (int ch=0; ch<nchunk; ch++){
    const float* x_c = x_in + (size_t)ch*Mc*D_;
    // 1. fused features + input projection (192-wide tile, 1 y-block)
    gemm_inp_w192<<<dim3(gmx, 1), 256, 0, stream>>>(x_c, inp_w, inp_b, h_c);
    // 2. ConvNeXt blocks
    for (int blk = 0; blk < 2; blk++){
      const float* dww = b_dw_w + blk*H_*9;     const float* dwb = b_dw_b + blk*H_;
      const float* lnw = b_ln_w + blk*H_;       const float* lnb = b_ln_b + blk*H_;
      const float* p1w = b_pw1_w + blk*HID_*H_; const float* p1b = b_pw1_b + blk*HID_;
      const float* gg  = b_grn_g + blk*HID_;    const float* gb  = b_grn_b + blk*HID_;
      const float* p2w = b_pw2_w + blk*H_*HID_; const float* p2b = b_pw2_b + blk*H_;
      dwconv_ln_wave<<<(int)(Mc/16), 256, 0, stream>>>(h_c, dww, dwb, lnw, lnb, yln_c);
      gemm_w192<1><<<dim3(gmx, 2), 256, 0, stream>>>(yln_c, p1w, p1b,
                                                     y1_c, nullptr, nullptr, gpart, HID_, H_);
      grn_combine_kernel<<<Bc, 384, 0, stream>>>(gpart, gg, scaleB);
      gemm_w192<2><<<dim3(gmx, 1), 256, 0, stream>>>(y1_c, p2w, p2b,
                                                     h_c, scaleB, gb, nullptr, H_, HID_);
    }
    // 3. output LN -> h_seq, save last-t rows
    out_ln_wave<<<(int)(Mc/4), 256, 0, stream>>>(h_c, out_ln_w, out_ln_b, yln_c, hlast, ch*Bc);
    // 4. fused Kalman projection GEMM (writes rp directly) + FMA-only scan
    gemm_t128<3><<<dim3(gmx, 1), 256, 0, stream>>>(yln_c, w_pad, b_pad,
                                                   rp_c, nullptr, nullptr, nullptr, 64, H_);
    kalman_scan_kernel<<<(Bc+3)/4, 64, 0, stream>>>(x_c, rp_c, xpost, ch*Bc, Bc);
  }
  // 5. GRU rollout v3 (proven): 128 blocks x 768 threads, BPB=2
  rollout_kernel<<<B_/BPB, RT_, 0, stream>>>(hlast, xpost, wT1, roll_in_b, wPack,
                                             gru_bih, gru_bhh, roll_ln_w, roll_ln_b,
                                             fc_rp_r_w, fc_rp_r_b, out);
  (void)in_sizes; (void)n_in; (void)out_size; (void)ws_size;
}

// Round 9
// 1975.573 us; speedup vs baseline: 1.2908x; 1.2908x over previous
//
#include <hip/hip_runtime.h>
#include <cstdint>
#include <cstddef>

#define B_    256
#define Q_    512
#define D_    32
#define H_    192
#define HID_  384
#define INCH_ 96
#define M_    (B_*Q_)    // 131072
#define WOUT_ 64
#define BPB   2          // batches per rollout block
#define RT_   768        // rollout threads: 4 quarters x 192, 12 waves
#define PI_F  3.14159265358979323846f
#define LDS_S 40         // padded LDS row stride in shorts (32 bf16 + 8 pad)

typedef unsigned int uint_t;
typedef __attribute__((ext_vector_type(8))) short short8v;   // 8 bf16 = 4 VGPR (guide §3)
typedef __attribute__((ext_vector_type(4))) float floatx4;

__device__ __forceinline__ float sigm(float x){ return 1.f/(1.f+expf(-x)); }
__device__ __forceinline__ float gelu_exact(float x){ return 0.5f*x*(1.f+erff(x*0.7071067811865475f)); }
__device__ __forceinline__ float4 f4sub(float4 a, float4 b){
  return make_float4(a.x-b.x, a.y-b.y, a.z-b.z, a.w-b.w);
}

// round-to-nearest-even fp32 -> bf16 hi/lo split: v ~= hi + lo with ~2^-17 rel error
__device__ __forceinline__ void f2bf2(float v, unsigned short& h, unsigned short& l){
  unsigned u = __float_as_uint(v);
  unsigned rh = u + 0x7FFFu + ((u>>16)&1u);
  h = (unsigned short)(rh>>16);
  float fh = __uint_as_float(((unsigned)h)<<16);
  float lo = v - fh;
  unsigned ul = __float_as_uint(lo);
  unsigned rl = ul + 0x7FFFu + ((ul>>16)&1u);
  l = (unsigned short)(rl>>16);
}

#define MFMA_BF16(a,b,c) __builtin_amdgcn_mfma_f32_16x16x32_bf16((a),(b),(c),0,0,0)

// ---------------- on-the-fly features: [x, dy, ddy] column chunk (bit-identical to feats_kernel) ----------------
__device__ __forceinline__ float4 feats_load(const float* __restrict__ x, int bt, int c){
  const int t = bt & 511;
  const int seg = c >> 5, d = c & 31;
  const float* xr = x + (size_t)bt*D_ + d;
  float4 x0 = *(const float4*)xr;
  if (seg == 0) return x0;
  if (t == 0) return make_float4(0.f,0.f,0.f,0.f);
  float4 x1 = *(const float4*)(xr - D_);
  float4 dy = f4sub(x0, x1);
  if (seg == 1) return dy;
  if (t == 1) return dy;                 // dym1 = 0 -> ddy = dy
  float4 x2 = *(const float4*)(xr - 2*D_);
  float4 dym1 = f4sub(x1, x2);
  return f4sub(dy, dym1);
}

// ---------------- MFMA split-bf16 GEMM: 128x192 tile, BK=32, 4 waves, fp32-grade accuracy ----------------
// D = A*B^T via 3 bf16 MFMAs per product tile: ah*bh + ah*bl + al*bh (al*bl ~2^-18 dropped).
// MODE 1 (pw1): out = gelu(acc+bias), + GRN column sum-of-squares partials -> gpart
// MODE 2 (pw2): A affine (scale/grnb) before split, C += acc+bias
// Fragment layouts (guide cdna4 16x16x32_bf16, m89-verified C/D):
//   A(i,k): lane i+16*(k>>3), slot k&7 ; B(k,j): lane j+16*(k>>3), slot k&7
//   D(i,j): lane j+16*(i>>2), reg i&3
// LDS rows padded to 40 shorts -> 16B-aligned ds_read_b128, ~2-way banks (free).
// launch_bounds(256,2) => 256-VGPR cap (est ~160 used) — spill-proof by construction.
template<int MODE>
__global__ __launch_bounds__(256,2) void gemm_mfma(
    const float* __restrict__ Af,
    const float* __restrict__ W,  const float* __restrict__ bias,
    float* __restrict__ Cf,
    const float* __restrict__ scale, const float* __restrict__ grnb,
    float* __restrict__ gpart,
    int N, int K)
{
  __shared__ __align__(16) unsigned short smem[25600];  // Ah[128][40] Al[128][40] Bh[192][40] Bl[192][40]
  unsigned short* Ah = smem;
  unsigned short* Al = smem + 128*LDS_S;
  unsigned short* Bh = smem + 256*LDS_S;
  unsigned short* Bl = smem + 256*LDS_S + 192*LDS_S;

  const int tid  = threadIdx.x;
  const int lane = tid & 63;
  const int wv   = tid >> 6;          // wave 0..3 -> rows [wv*32, wv*32+32)
  const int l15  = lane & 15;
  const int lg   = lane >> 4;         // 0..3
  const int bm = blockIdx.x*128, bn = blockIdx.y*192;

  floatx4 acc[2][12];
  #pragma unroll
  for (int i=0;i<2;i++)
    #pragma unroll
    for (int j=0;j<12;j++) acc[i][j] = (floatx4){0.f,0.f,0.f,0.f};

  const int arow = tid >> 1, akq = (tid & 1)*16;   // A: 128 rows x 2 half-rows of 16 k
  const float* gA = Af + (size_t)(bm+arow)*K;
  const float* srow = (MODE==2) ? (scale + (size_t)(bm>>9)*HID_) : nullptr;

  for (int k0=0; k0<K; k0+=32){
    // ---- stage A (fp32 -> hi/lo bf16) ----
    #pragma unroll
    for (int i=0;i<4;i++){
      float4 v = *(const float4*)(gA + k0 + akq + 4*i);
      if (MODE==2){
        int c = k0 + akq + 4*i;
        float4 sc = *(const float4*)(srow+c);
        float4 gb = *(const float4*)(grnb+c);
        v.x = v.x*sc.x+gb.x; v.y = v.y*sc.y+gb.y;
        v.z = v.z*sc.z+gb.z; v.w = v.w*sc.w+gb.w;
      }
      unsigned short h0,h1,h2,h3,l0,l1,l2,l3;
      f2bf2(v.x,h0,l0); f2bf2(v.y,h1,l1); f2bf2(v.z,h2,l2); f2bf2(v.w,h3,l3);
      uint2 uh; uh.x = (unsigned)h0 | ((unsigned)h1<<16); uh.y = (unsigned)h2 | ((unsigned)h3<<16);
      uint2 ul; ul.x = (unsigned)l0 | ((unsigned)l1<<16); ul.y = (unsigned)l2 | ((unsigned)l3<<16);
      *(uint2*)&Ah[arow*LDS_S + akq + 4*i] = uh;
      *(uint2*)&Al[arow*LDS_S + akq + 4*i] = ul;
    }
    // ---- stage B (weights fp32 -> hi/lo bf16); 192 rows x 2 halves = 384 units ----
    for (int idx = tid; idx < 384; idx += 256){
      int br = idx >> 1, bkq = (idx & 1)*16;
      const float* gb = W + (size_t)(bn+br)*K + k0 + bkq;
      #pragma unroll
      for (int i=0;i<4;i++){
        float4 v = *(const float4*)(gb + 4*i);
        unsigned short h0,h1,h2,h3,l0,l1,l2,l3;
        f2bf2(v.x,h0,l0); f2bf2(v.y,h1,l1); f2bf2(v.z,h2,l2); f2bf2(v.w,h3,l3);
        uint2 uh; uh.x = (unsigned)h0 | ((unsigned)h1<<16); uh.y = (unsigned)h2 | ((unsigned)h3<<16);
        uint2 ul; ul.x = (unsigned)l0 | ((unsigned)l1<<16); ul.y = (unsigned)l2 | ((unsigned)l3<<16);
        *(uint2*)&Bh[br*LDS_S + bkq + 4*i] = uh;
        *(uint2*)&Bl[br*LDS_S + bkq + 4*i] = ul;
      }
    }
    __syncthreads();

    // ---- MFMA: one 16x16x32 k-tile per step ----
    const int a0off = (wv*32 + l15)*LDS_S + 8*lg;
    const int a1off = a0off + 16*LDS_S;
    short8v ah0 = *(const short8v*)&Ah[a0off];
    short8v al0 = *(const short8v*)&Al[a0off];
    short8v ah1 = *(const short8v*)&Ah[a1off];
    short8v al1 = *(const short8v*)&Al[a1off];
    #pragma unroll
    for (int ct=0; ct<12; ct++){
      const int boff = (ct*16 + l15)*LDS_S + 8*lg;
      short8v bh = *(const short8v*)&Bh[boff];
      short8v bl = *(const short8v*)&Bl[boff];
      acc[0][ct] = MFMA_BF16(ah0, bh, acc[0][ct]);
      acc[0][ct] = MFMA_BF16(ah0, bl, acc[0][ct]);
      acc[0][ct] = MFMA_BF16(al0, bh, acc[0][ct]);
      acc[1][ct] = MFMA_BF16(ah1, bh, acc[1][ct]);
      acc[1][ct] = MFMA_BF16(ah1, bl, acc[1][ct]);
      acc[1][ct] = MFMA_BF16(al1, bh, acc[1][ct]);
    }
    __syncthreads();
  }

  // ---- epilogue ----
  if (MODE==1){
    float* gq = (float*)smem;   // reuse: [192 cols][16 slots]
    #pragma unroll
    for (int ct=0; ct<12; ct++){
      const int col = bn + ct*16 + l15;
      const float b = bias[col];
      float qc = 0.f;
      #pragma unroll
      for (int rt=0; rt<2; rt++){
        const int rbase = bm + wv*32 + rt*16 + lg*4;
        #pragma unroll
        for (int r=0;r<4;r++){
          float v = gelu_exact(acc[rt][ct][r] + b);
          Cf[(size_t)(rbase+r)*N + col] = v;
          qc += v*v;
        }
      }
      gq[(ct*16+l15)*16 + (wv*4+lg)] = qc;
    }
    __syncthreads();
    if (tid < 192){
      float s = 0.f;
      #pragma unroll
      for (int j=0;j<16;j++) s += gq[tid*16+j];
      const int slot = (bm>>7)&3, b = bm>>9;
      gpart[((size_t)(b*4+slot))*HID_ + bn + tid] = s;
    }
  } else {
    #pragma unroll
    for (int ct=0; ct<12; ct++){
      const int col = bn + ct*16 + l15;
      const float b = bias[col];
      #pragma unroll
      for (int rt=0; rt<2; rt++){
        const int rbase = bm + wv*32 + rt*16 + lg*4;
        #pragma unroll
        for (int r=0;r<4;r++){
          size_t off = (size_t)(rbase+r)*N + col;
          Cf[off] = Cf[off] + acc[rt][ct][r] + b;
        }
      }
    }
  }
}

// ---------------- input GEMM: fused feature synthesis, 128x192 fp32 tile (N=192, K=96) ----------------
__global__ __launch_bounds__(256,2) void gemm_inp_w192(
    const float* __restrict__ x,
    const float* __restrict__ W,  const float* __restrict__ bias,
    float* __restrict__ Cf)
{
  __shared__ float smem[16*128 + 16*192];
  float* AsB = smem;
  float* BsB = smem + 16*128;
  const int tid = threadIdx.x;
  const int bm = blockIdx.x*128;
  const int tx = tid & 15, ty = tid >> 4;
  const int arow = tid >> 1, ak = (tid & 1)*4;
  const int br = tid >> 2,  bk = (tid & 3)*4;
  const int K = INCH_, N = H_;

  float acc[8][12];
  #pragma unroll
  for (int i=0;i<8;i++)
    #pragma unroll
    for (int j=0;j<12;j++) acc[i][j]=0.f;

  const float* gB0 = W + (size_t)(br)*K;
  const float* gB1 = W + (size_t)(br+64)*K;
  const float* gB2 = W + (size_t)(br+128)*K;

  for (int k0=0;k0<K;k0+=16){
    float4 va0 = feats_load(x, bm+arow, k0+ak);
    float4 va1 = feats_load(x, bm+arow, k0+ak+8);
    float4 vb0 = *(const float4*)(gB0 + k0 + bk);
    float4 vb1 = *(const float4*)(gB1 + k0 + bk);
    float4 vb2 = *(const float4*)(gB2 + k0 + bk);
    AsB[(ak+0)*128+arow]=va0.x; AsB[(ak+1)*128+arow]=va0.y; AsB[(ak+2)*128+arow]=va0.z; AsB[(ak+3)*128+arow]=va0.w;
    AsB[(ak+8)*128+arow]=va1.x; AsB[(ak+9)*128+arow]=va1.y; AsB[(ak+10)*128+arow]=va1.z; AsB[(ak+11)*128+arow]=va1.w;
    BsB[(bk+0)*192+br]=vb0.x; BsB[(bk+1)*192+br]=vb0.y; BsB[(bk+2)*192+br]=vb0.z; BsB[(bk+3)*192+br]=vb0.w;
    BsB[(bk+0)*192+br+64]=vb1.x; BsB[(bk+1)*192+br+64]=vb1.y; BsB[(bk+2)*192+br+64]=vb1.z; BsB[(bk+3)*192+br+64]=vb1.w;
    BsB[(bk+0)*192+br+128]=vb2.x; BsB[(bk+1)*192+br+128]=vb2.y; BsB[(bk+2)*192+br+128]=vb2.z; BsB[(bk+3)*192+br+128]=vb2.w;
    __syncthreads();
    #pragma unroll
    for (int kk=0;kk<16;kk++){
      float4 a0 = *(const float4*)&AsB[kk*128 + ty*8];
      float4 a1 = *(const float4*)&AsB[kk*128 + ty*8 + 4];
      float4 b0 = *(const float4*)&BsB[kk*192 + tx*12];
      float4 b1 = *(const float4*)&BsB[kk*192 + tx*12 + 4];
      float4 b2 = *(const float4*)&BsB[kk*192 + tx*12 + 8];
      float ar[8] = {a0.x,a0.y,a0.z,a0.w,a1.x,a1.y,a1.z,a1.w};
      #pragma unroll
      for (int i=0;i<8;i++){
        acc[i][0] += ar[i]*b0.x; acc[i][1] += ar[i]*b0.y; acc[i][2] += ar[i]*b0.z; acc[i][3] += ar[i]*b0.w;
        acc[i][4] += ar[i]*b1.x; acc[i][5] += ar[i]*b1.y; acc[i][6] += ar[i]*b1.z; acc[i][7] += ar[i]*b1.w;
        acc[i][8] += ar[i]*b2.x; acc[i][9] += ar[i]*b2.y; acc[i][10]+= ar[i]*b2.z; acc[i][11]+= ar[i]*b2.w;
      }
    }
    __syncthreads();
  }

  const int o0 = tx*12;
  float4 bb0 = *(const float4*)(bias + o0);
  float4 bb1 = *(const float4*)(bias + o0 + 4);
  float4 bb2 = *(const float4*)(bias + o0 + 8);
  #pragma unroll
  for (int i=0;i<8;i++){
    int m = bm + ty*8 + i;
    float* crow = Cf + (size_t)m*N + o0;
    float4 v0, v1, v2;
    v0.x=acc[i][0]+bb0.x; v0.y=acc[i][1]+bb0.y; v0.z=acc[i][2]+bb0.z; v0.w=acc[i][3]+bb0.w;
    v1.x=acc[i][4]+bb1.x; v1.y=acc[i][5]+bb1.y; v1.z=acc[i][6]+bb1.z; v1.w=acc[i][7]+bb1.w;
    v2.x=acc[i][8]+bb2.x; v2.y=acc[i][9]+bb2.y; v2.z=acc[i][10]+bb2.z; v2.w=acc[i][11]+bb2.w;
    *(float4*)(crow+0) = v0; *(float4*)(crow+4) = v1; *(float4*)(crow+8) = v2;
  }
}

// ---------------- 128x64x16 fp32 GEMM (kept only for MODE 3: Kalman projection, N=64) ----------------
template<int MODE>
__global__ __launch_bounds__(256,4) void gemm_t128(
    const float* __restrict__ Af,
    const float* __restrict__ W,  const float* __restrict__ bias,
    float* __restrict__ Cf,
    const float* __restrict__ scale, const float* __restrict__ grnb,
    float* __restrict__ gpart,
    int N, int K)
{
  __shared__ float As[16][128];
  __shared__ float Bs[16][64];
  const int tid = threadIdx.x;
  const int bm = blockIdx.x*128, bn = blockIdx.y*64;
  const int tx = tid & 15, ty = tid >> 4;
  const int arow = tid >> 1, ak = (tid & 1)*4;
  const int brow = tid >> 2, bk = (tid & 3)*4;

  float acc[8][4];
  #pragma unroll
  for (int i=0;i<8;i++)
    #pragma unroll
    for (int j=0;j<4;j++) acc[i][j]=0.f;

  const float* gA = Af + (size_t)(bm+arow)*K;
  const float* gB = W  + (size_t)(bn+brow)*K;

  for (int k0=0;k0<K;k0+=16){
    float4 va0 = *(const float4*)(gA + k0 + ak);
    float4 va1 = *(const float4*)(gA + k0 + ak + 8);
    float4 vb  = *(const float4*)(gB + k0 + bk);
    As[ak+0][arow]=va0.x; As[ak+1][arow]=va0.y; As[ak+2][arow]=va0.z; As[ak+3][arow]=va0.w;
    As[ak+8][arow]=va1.x; As[ak+9][arow]=va1.y; As[ak+10][arow]=va1.z; As[ak+11][arow]=va1.w;
    Bs[bk+0][brow]=vb.x; Bs[bk+1][brow]=vb.y; Bs[bk+2][brow]=vb.z; Bs[bk+3][brow]=vb.w;
    __syncthreads();
    #pragma unroll
    for (int kk=0;kk<16;kk++){
      float4 a0 = *(const float4*)&As[kk][ty*8];
      float4 a1 = *(const float4*)&As[kk][ty*8+4];
      float4 b  = *(const float4*)&Bs[kk][tx*4];
      float ar[8] = {a0.x,a0.y,a0.z,a0.w,a1.x,a1.y,a1.z,a1.w};
      #pragma unroll
      for (int i=0;i<8;i++){
        acc[i][0] += ar[i]*b.x; acc[i][1] += ar[i]*b.y;
        acc[i][2] += ar[i]*b.z; acc[i][3] += ar[i]*b.w;
      }
    }
    __syncthreads();
  }

  const int o0 = bn + tx*4;
  float4 b0 = *(const float4*)(bias + o0);

  if (MODE==3){
    #pragma unroll
    for (int i=0;i<8;i++){
      int m = bm + ty*8 + i;
      float* ob = Cf + (size_t)m*34;
      float vx = acc[i][0]+b0.x, vy = acc[i][1]+b0.y;
      float vz = acc[i][2]+b0.z, vw = acc[i][3]+b0.w;
      if (o0 == 0){
        float rho = 1.25f*sigm(vx);
        float phi = PI_F*tanhf(vy);
        ob[0] = rho*cosf(phi); ob[1] = rho*sinf(phi);
        ob[2] = sigm(vz); ob[3] = sigm(vw);
      } else if (o0 <= 28){
        ob[o0+0]=sigm(vx); ob[o0+1]=sigm(vy); ob[o0+2]=sigm(vz); ob[o0+3]=sigm(vw);
      } else if (o0 == 32){
        ob[32]=sigm(vx); ob[33]=sigm(vy);
      }
    }
    return;
  }
  (void)gpart; (void)scale; (void)grnb;
}

// ---------------- depthwise conv (k=9, edge pad) + wave-local LN: 4 waves, 16 timesteps, 1 barrier ----------------
__global__ __launch_bounds__(256) void dwconv_ln_wave(
  const float* __restrict__ h, const float* __restrict__ dww, const float* __restrict__ dwb,
  const float* __restrict__ lnw, const float* __restrict__ lnb, float* __restrict__ yln)
{
  __shared__ float sh[24][192];
  const int tid  = threadIdx.x;
  const int lane = tid & 63;
  const int wv   = tid >> 6;
  const int t0 = (blockIdx.x & 31) * 16;
  const size_t base = (size_t)(blockIdx.x >> 5) * Q_ * H_;
  #pragma unroll
  for (int i = tid; i < 24*192; i += 256){
    int r = i / 192, c = i - r*192;
    int tt = t0 - 4 + r; tt = tt<0?0:(tt>511?511:tt);
    sh[r][c] = h[base + (size_t)tt*H_ + c];
  }
  const int c0 = lane, c1 = lane+64, c2 = lane+128;
  float w0[9], w1[9], w2[9];
  #pragma unroll
  for (int k=0;k<9;k++){ w0[k]=dww[c0*9+k]; w1[k]=dww[c1*9+k]; w2[k]=dww[c2*9+k]; }
  const float db0=dwb[c0], db1=dwb[c1], db2=dwb[c2];
  const float lw0=lnw[c0], lw1=lnw[c1], lw2=lnw[c2];
  const float lb0=lnb[c0], lb1=lnb[c1], lb2=lnb[c2];
  __syncthreads();
  for (int it=0; it<4; it++){
    const int i = it*4 + wv;
    float a0=db0, a1=db1, a2=db2;
    #pragma unroll
    for (int k=0;k<9;k++){
      a0 += w0[k]*sh[i+k][c0];
      a1 += w1[k]*sh[i+k][c1];
      a2 += w2[k]*sh[i+k][c2];
    }
    float s = a0+a1+a2;
    float qq = a0*a0 + a1*a1 + a2*a2;
    #pragma unroll
    for (int off=32; off>0; off>>=1){ s += __shfl_down(s,off); qq += __shfl_down(qq,off); }
    s = __shfl(s, 0); qq = __shfl(qq, 0);
    float mean = s*(1.f/H_);
    float var  = qq*(1.f/H_) - mean*mean;
    float r = rsqrtf(var + 1e-5f);
    float* ob = yln + base + (size_t)(t0+i)*H_;
    ob[c0] = (a0-mean)*r*lw0 + lb0;
    ob[c1] = (a1-mean)*r*lw1 + lb1;
    ob[c2] = (a2-mean)*r*lw2 + lb2;
  }
}

// ---------------- output LayerNorm, wave-local (4 rows/block, no LDS, no barriers) ----------------
__global__ __launch_bounds__(256) void out_ln_wave(
  const float* __restrict__ h, const float* __restrict__ lnw, const float* __restrict__ lnb,
  float* __restrict__ o, float* __restrict__ hlast, int b0)
{
  const int tid  = threadIdx.x;
  const int lane = tid & 63;
  const int wv   = tid >> 6;
  const int bt = blockIdx.x*4 + wv;
  const float* hr = h + (size_t)bt*H_;
  float v0 = hr[lane], v1 = hr[lane+64], v2 = hr[lane+128];
  float s = v0+v1+v2;
  float qq = v0*v0 + v1*v1 + v2*v2;
  #pragma unroll
  for (int off=32; off>0; off>>=1){ s += __shfl_down(s,off); qq += __shfl_down(qq,off); }
  s = __shfl(s, 0); qq = __shfl(qq, 0);
  float mean = s*(1.f/H_);
  float var  = qq*(1.f/H_) - mean*mean;
  float r = rsqrtf(var + 1e-5f);
  const float r0 = (v0-mean)*r*lnw[lane]     + lnb[lane];
  const float r1 = (v1-mean)*r*lnw[lane+64]  + lnb[lane+64];
  const float r2 = (v2-mean)*r*lnw[lane+128] + lnb[lane+128];
  float* orow = o + (size_t)bt*H_;
  orow[lane] = r0; orow[lane+64] = r1; orow[lane+128] = r2;
  if ((bt & 511) == 511){
    float* hl = hlast + (size_t)(b0 + (bt>>9))*H_;
    hl[lane] = r0; hl[lane+64] = r1; hl[lane+128] = r2;
  }
}

// ---------------- GRN combine: 4 slot partials -> scale ----------------
__global__ __launch_bounds__(384) void grn_combine_kernel(
  const float* __restrict__ gpart, const float* __restrict__ grn_g, float* __restrict__ scale)
{
  __shared__ float r[384];
  const int c = threadIdx.x;
  const int b = blockIdx.x;
  const float* p = gpart + (size_t)b*4*HID_;
  float s = ((p[c] + p[HID_+c]) + p[2*HID_+c]) + p[3*HID_+c];
  float gx = sqrtf(s);
  r[c] = gx;
  __syncthreads();
  if (c < 64){
    float v = r[c]+r[c+64]+r[c+128]+r[c+192]+r[c+256]+r[c+320];
    #pragma unroll
    for (int off=32; off>0; off>>=1) v += __shfl_down(v,off);
    if (c==0) r[0]=v;
  }
  __syncthreads();
  float mean = r[0]*(1.f/HID_);
  scale[(size_t)b*HID_ + c] = 1.f + grn_g[c]*gx/(mean + 1e-6f);
}

// ---------------- pack fc_rp / fc_gain into padded (64,192) W ----------------
__global__ void pack_w_kernel(const float* __restrict__ frw, const float* __restrict__ frb,
                              const float* __restrict__ fgw, const float* __restrict__ fgb,
                              float* __restrict__ w_pad, float* __restrict__ b_pad)
{
  int idx = blockIdx.x*256 + threadIdx.x;
  if (idx >= 64*192) return;
  int o = idx / 192, k = idx % 192;
  float v = 0.f;
  if (o < 2) v = frw[o*192+k]; else if (o < 34) v = fgw[(o-2)*192+k];
  w_pad[idx] = v;
  if (k == 0){
    float bv = 0.f;
    if (o < 2) bv = frb[o]; else if (o < 34) bv = fgb[o-2];
    b_pad[o] = bv;
  }
}

// ---------------- sequential Kalman scan (FMA-only) ----------------
__global__ __launch_bounds__(64) void kalman_scan_kernel(
  const float* __restrict__ x_c, const float* __restrict__ rp, float* __restrict__ xpost,
  int b0, int Bc)
{
  const int lane = threadIdx.x;
  const int bl = blockIdx.x*4 + (lane>>4);
  if (bl >= Bc) return;
  const int m = lane & 15;
  const float* xb  = x_c + (size_t)bl*Q_*D_;
  const float* rpb = rp  + (size_t)bl*Q_*34;
  float re = xb[m], im = xb[16+m];
  for (int t=0;t<Q_;t++){
    const float* r = rpb + (size_t)t*34;
    float rc = r[0], rs = r[1];
    float g0 = r[2+m], g1 = r[18+m];
    float y0 = xb[(size_t)t*D_ + m], y1v = xb[(size_t)t*D_ + 16 + m];
    float pr  = rc*re - rs*im;
    float pim = rs*re + rc*im;
    re = pr  + g0*(y0  - pr);
    im = pim + g1*(y1v - pim);
  }
  xpost[(b0+bl)*D_ + m] = re;
  xpost[(b0+bl)*D_ + 16 + m] = im;
}

// ---------------- rollout weight prep: wT1[k][o] + packed [k][o][8] gate block ----------------
__global__ void prep_rollout_kernel(const float* __restrict__ riw, const float* __restrict__ wih,
                                    const float* __restrict__ whh,
                                    float* __restrict__ wT1, float* __restrict__ wPack)
{
  int idx = blockIdx.x*256 + threadIdx.x;
  if (idx < 224*192){
    int o = idx % 192, k = idx / 192;
    wT1[idx] = riw[o*224 + k];
    return;
  }
  idx -= 224*192;
  if (idx < 192*192){
    int o = idx % 192, k = idx / 192;
    float* w = wPack + ((size_t)k*192 + o)*8;
    w[0] = wih[(0*192+o)*192 + k];
    w[1] = wih[(1*192+o)*192 + k];
    w[2] = wih[(2*192+o)*192 + k];
    w[3] = whh[(0*192+o)*192 + k];
    w[4] = whh[(1*192+o)*192 + k];
    w[5] = whh[(2*192+o)*192 + k];
    w[6] = 0.f; w[7] = 0.f;
  }
}

// ---------------- GRU rollout v3 (proven 890us): BPB=2, 128 blocks ----------------
// - wT1 (phase-A weights) live in 56 registers per thread, loaded once (step-invariant).
//   NOTE: phase-B weights stay as L2 streams; promoting them (288 floats) exceeds SROA's
//   limit and spills to scratch (R3: 3.5 GB scratch traffic, 2.3 ms). Do not retry.
// - Per-CU L1-fill bound on the 1.18 MB/step wPack stream — invariant to BPB (R1/R2 evidence).
__global__ __launch_bounds__(RT_,3) void rollout_kernel(
  const float* __restrict__ hlast, const float* __restrict__ xpost,
  const float* __restrict__ wT1,  const float* __restrict__ rib_,
  const float* __restrict__ wPack,
  const float* __restrict__ bih,  const float* __restrict__ bhh,
  const float* __restrict__ lnw,  const float* __restrict__ lnb,
  const float* __restrict__ frw,  const float* __restrict__ frb,
  float* __restrict__ out)
{
  const int tid = threadIdx.x;
  const int q   = tid / 192;        // quarter 0..3 (wave-aligned: 192 = 3 waves)
  const int o   = tid - q*192;      // channel 0..191
  const int bb  = blockIdx.x*BPB;

  __shared__ float hT[192][2];      // h state, batch-major
  __shared__ float xT[192][2];      // x = tanh(W1 [h;c]), batch-major
  __shared__ float cT[32][2];       // curr (Kalman state), batch-major
  __shared__ float pA[4][2][192];   // phase-A partials [quarter][batch][o]
  __shared__ float pB[4][12][192];  // phase-B partials [quarter][batch*6+gate][o]
  __shared__ float rsum[2][3][4];   // [batch][wave][S1,S2,S3,S4]

  // ---- init state ----
  if (q < 2){
    hT[o][q] = hlast[(size_t)(bb+q)*H_ + o];
    if (o < 32) cT[o][q] = xpost[(bb+q)*D_ + o];
  }

  const float w_ln = lnw[o], b_ln = lnb[o];
  const float fr0  = frw[o], fr1  = frw[192+o];
  const float fb0 = frb[0],  fb1 = frb[1];
  const float bi0 = bih[o], bi1 = bih[192+o], bi2 = bih[384+o];
  const float bh0 = bhh[o], bh1 = bhh[192+o], bh2 = bhh[384+o];
  const float rib = rib_[o];
  const float u0 = w_ln*fr0, u1 = w_ln*fr1;      // for fused projection
  const float t0c = b_ln*fr0, t1c = b_ln*fr1;

  // ---- phase-A weights in registers (step-invariant) ----
  float wreg[56];
  if (q < 3){
    const int kb = 56*q;
    #pragma unroll
    for (int i=0;i<56;i++) wreg[i] = wT1[(kb+i)*192+o];
  } else {
    #pragma unroll
    for (int i=0;i<24;i++) wreg[i] = wT1[(168+i)*192+o];
    #pragma unroll
    for (int i=0;i<32;i++) wreg[24+i] = wT1[(192+i)*192+o];
  }

  // ---- one-time constants: C0=sum(u0), C1=sum(u1), K0=sum(lnb*fr0)+fb0, K1=sum(lnb*fr1)+fb1 ----
  {
    float c0=u0, c1=u1, k0=t0c, k1=t1c;
    #pragma unroll
    for (int off=32; off>0; off>>=1){
      c0 += __shfl_down(c0,off); c1 += __shfl_down(c1,off);
      k0 += __shfl_down(k0,off); k1 += __shfl_down(k1,off);
    }
    if (q==0 && (o&63)==0){
      int w = o>>6;
      rsum[0][w][0]=c0; rsum[0][w][1]=c1; rsum[0][w][2]=k0; rsum[0][w][3]=k1;
    }
  }
  __syncthreads();
  const float C0 = rsum[0][0][0]+rsum[0][1][0]+rsum[0][2][0];
  const float C1 = rsum[0][0][1]+rsum[0][1][1]+rsum[0][2][1];
  const float K0 = rsum[0][0][2]+rsum[0][1][2]+rsum[0][2][2] + fb0;
  const float K1 = rsum[0][0][3]+rsum[0][1][3]+rsum[0][2][3] + fb1;

  for (int s=0; s<WOUT_; s++){
    // ---- phase A: partial x = W1 @ [h;c], K=224 split 4-way, weights in regs ----
    float a0=0.f, a1=0.f;
    if (q < 3){
      const int kb = 56*q;
      #pragma unroll
      for (int i=0;i<56;i++){
        float2 h2 = *(const float2*)&hT[kb+i][0];
        a0 += wreg[i]*h2.x; a1 += wreg[i]*h2.y;
      }
    } else {
      #pragma unroll
      for (int i=0;i<24;i++){
        float2 h2 = *(const float2*)&hT[168+i][0];
        a0 += wreg[i]*h2.x; a1 += wreg[i]*h2.y;
      }
      #pragma unroll
      for (int i=0;i<32;i++){
        float2 c2 = *(const float2*)&cT[i][0];
        a0 += wreg[24+i]*c2.x; a1 += wreg[24+i]*c2.y;
      }
    }
    pA[q][0][o]=a0; pA[q][1][o]=a1;
    __syncthreads();

    // ---- x combine: quarter j (<2) owns batch j ----
    if (q < 2){
      xT[o][q] = tanhf(rib + pA[0][q][o] + pA[1][q][o] + pA[2][q][o] + pA[3][q][o]);
    }
    __syncthreads();

    // ---- phase B: partial gates, K=192 split 4-way (48 each) ----
    float accx[2][3] = {{0.f,0.f,0.f},{0.f,0.f,0.f}};
    float acch[2][3] = {{0.f,0.f,0.f},{0.f,0.f,0.f}};
    {
      const int kb2 = 48*q;
      #pragma unroll 4
      for (int i=0;i<48;i++){
        const int k = kb2+i;
        const float4* wp = (const float4*)(wPack + ((size_t)k*192 + o)*8);
        const float4 wA = wp[0];
        const float4 wB = wp[1];
        const float2 xx = *(const float2*)&xT[k][0];
        const float2 hh = *(const float2*)&hT[k][0];
        accx[0][0] += wA.x*xx.x; accx[0][1] += wA.y*xx.x; accx[0][2] += wA.z*xx.x;
        accx[1][0] += wA.x*xx.y; accx[1][1] += wA.y*xx.y; accx[1][2] += wA.z*xx.y;
        acch[0][0] += wA.w*hh.x; acch[0][1] += wB.x*hh.x; acch[0][2] += wB.y*hh.x;
        acch[1][0] += wA.w*hh.y; acch[1][1] += wB.x*hh.y; acch[1][2] += wB.y*hh.y;
      }
    }
    #pragma unroll
    for (int j=0;j<2;j++){
      #pragma unroll
      for (int g=0;g<3;g++){
        pB[q][j*6+g][o]   = accx[j][g];
        pB[q][j*6+3+g][o] = acch[j][g];
      }
    }
    __syncthreads();

    // ---- gate combine + fused 4-sum wave reduction (quarters 0/1 own batch q) ----
    float pre = 0.f;
    if (q < 2){
      const int g6 = q*6;
      float P0 = bi0 + pB[0][g6+0][o]+pB[1][g6+0][o]+pB[2][g6+0][o]+pB[3][g6+0][o];
      float P1 = bi1 + pB[0][g6+1][o]+pB[1][g6+1][o]+pB[2][g6+1][o]+pB[3][g6+1][o];
      float P2 = bi2 + pB[0][g6+2][o]+pB[1][g6+2][o]+pB[2][g6+2][o]+pB[3][g6+2][o];
      float Q0 = bh0 + pB[0][g6+3][o]+pB[1][g6+3][o]+pB[2][g6+3][o]+pB[3][g6+3][o];
      float Q1 = bh1 + pB[0][g6+4][o]+pB[1][g6+4][o]+pB[2][g6+4][o]+pB[3][g6+4][o];
      float Q2 = bh2 + pB[0][g6+5][o]+pB[1][g6+5][o]+pB[2][g6+5][o]+pB[3][g6+5][o];
      float rg = sigm(P0+Q0), zz = sigm(P1+Q1);
      float nn = tanhf(P2 + rg*Q2);
      pre = (1.f-zz)*nn + zz*hT[o][q];
      float s1 = pre, s2 = pre*pre, s3 = pre*u0, s4 = pre*u1;
      #pragma unroll
      for (int off=32; off>0; off>>=1){
        s1 += __shfl_down(s1,off); s2 += __shfl_down(s2,off);
        s3 += __shfl_down(s3,off); s4 += __shfl_down(s4,off);
      }
      if ((o&63)==0){
        int w = o>>6;
        rsum[q][w][0]=s1; rsum[q][w][1]=s2; rsum[q][w][2]=s3; rsum[q][w][3]=s4;
      }
    }
    __syncthreads();

    // ---- concurrent tail: LN update (q<2) || Kalman rotate (q>=2, o<16) ----
    if (q < 2){
      float S1 = rsum[q][0][0]+rsum[q][1][0]+rsum[q][2][0];
      float S2 = rsum[q][0][1]+rsum[q][1][1]+rsum[q][2][1];
      float mu  = S1*(1.f/192.f);
      float var = S2*(1.f/192.f) - mu*mu;
      float r = rsqrtf(var+1e-5f);
      hT[o][q] = (pre-mu)*r*w_ln + b_ln;
    } else if (o < 16){
      const int j = q-2;
      float S1 = rsum[j][0][0]+rsum[j][1][0]+rsum[j][2][0];
      float S2 = rsum[j][0][1]+rsum[j][1][1]+rsum[j][2][1];
      float S3 = rsum[j][0][2]+rsum[j][1][2]+rsum[j][2][2];
      float S4 = rsum[j][0][3]+rsum[j][1][3]+rsum[j][2][3];
      float mu  = S1*(1.f/192.f);
      float var = S2*(1.f/192.f) - mu*mu;
      float r = rsqrtf(var+1e-5f);
      float proj0 = r*(S3 - mu*C0) + K0;
      float proj1 = r*(S4 - mu*C1) + K1;
      float rho = 1.25f*sigm(proj0);
      float phi = PI_F*tanhf(proj1);
      float rc = rho*cosf(phi), rs = rho*sinf(phi);
      float re = cT[o][j], im = cT[o+16][j];
      float nre = rc*re - rs*im;
      float nim = rs*re + rc*im;
      cT[o][j] = nre; cT[o+16][j] = nim;
      float* ob = out + ((size_t)(bb+j)*WOUT_ + s)*D_;
      ob[o] = nre; ob[o+16] = nim;
    }
    __syncthreads();
  }
}

// ---------------- host launch ----------------
extern "C" void kernel_launch(void* const* d_in, const int* in_sizes, int n_in,
                              void* d_out, int out_size, void* d_ws, size_t ws_size,
                              hipStream_t stream)
{
  const float* x_in     = (const float*)d_in[0];
  const float* inp_w    = (const float*)d_in[1];
  const float* inp_b    = (const float*)d_in[2];
  const float* b_dw_w   = (const float*)d_in[3];
  const float* b_dw_b   = (const float*)d_in[4];
  const float* b_ln_w   = (const float*)d_in[5];
  const float* b_ln_b   = (const float*)d_in[6];
  const float* b_pw1_w  = (const float*)d_in[7];
  const float* b_pw1_b  = (const float*)d_in[8];
  const float* b_grn_g  = (const float*)d_in[9];
  const float* b_grn_b  = (const float*)d_in[10];
  const float* b_pw2_w  = (const float*)d_in[11];
  const float* b_pw2_b  = (const float*)d_in[12];
  const float* out_ln_w = (const float*)d_in[13];
  const float* out_ln_b = (const float*)d_in[14];
  const float* fc_rp_w  = (const float*)d_in[15];
  const float* fc_rp_b  = (const float*)d_in[16];
  const float* fc_gain_w= (const float*)d_in[17];
  const float* fc_gain_b= (const float*)d_in[18];
  const float* roll_in_w= (const float*)d_in[19];
  const float* roll_in_b= (const float*)d_in[20];
  const float* gru_wih  = (const float*)d_in[21];
  const float* gru_whh  = (const float*)d_in[22];
  const float* gru_bih  = (const float*)d_in[23];
  const float* gru_bhh  = (const float*)d_in[24];
  const float* roll_ln_w= (const float*)d_in[25];
  const float* roll_ln_b= (const float*)d_in[26];
  const float* fc_rp_r_w= (const float*)d_in[27];
  const float* fc_rp_r_b= (const float*)d_in[28];
  float* out = (float*)d_out;

  // ---- adaptive chunking ----
  const size_t SMAL_FLOATS = 899136 + 4096;
  size_t ws_floats = ws_size / 4;
  int nchunk = 256;
  const int cand[9] = {1,2,4,8,16,32,64,128,256};
  for (int ci=0; ci<9; ci++){
    size_t Mc_try = (size_t)M_ / cand[ci];
    if (Mc_try*768 + SMAL_FLOATS <= ws_floats){ nchunk = cand[ci]; break; }
  }
  const int    Bc = B_ / nchunk;
  const size_t Mc = (size_t)Bc * Q_;

  float* ws    = (float*)d_ws;
  float* h_c   = ws;
  float* yln_c = h_c   + Mc*192;
  float* mid_c = yln_c + Mc*192;
  float* smal  = mid_c + Mc*384;

  float* y1_c    = mid_c;
  float* rp_c    = mid_c;                // Mc*34 (y1 dead by then)

  float* scaleB = smal;                  // Bc*384 (reserve 98304)
  float* w_pad  = smal + 98304;          // 64*192
  float* b_pad  = w_pad + 12288;         // 64
  float* xpost  = b_pad + 64;            // B_*32
  float* hlast  = xpost + 8192;          // B_*192
  float* wT1    = hlast + 49152;         // 224*192
  float* wPack  = wT1 + 43008;           // 192*192*8
  float* gpart  = wPack + 294912;        // 4*Bc*384 (reserve 393216)

  // one-time weight prep
  pack_w_kernel<<<(64*192+255)/256, 256, 0, stream>>>(fc_rp_w, fc_rp_b, fc_gain_w, fc_gain_b, w_pad, b_pad);
  prep_rollout_kernel<<<(224*192+192*192+255)/256, 256, 0, stream>>>(roll_in_w, gru_wih, gru_whh, wT1, wPack);

  const int gmx = (int)(Mc/128);
  for (int ch=0; ch<nchunk; ch++){
    const float* x_c = x_in + (size_t)ch*Mc*D_;
    // 1. fused features + input projection (fp32, small)
    gemm_inp_w192<<<dim3(gmx, 1), 256, 0, stream>>>(x_c, inp_w, inp_b, h_c);
    // 2. ConvNeXt blocks — pw1/pw2 on the matrix cores (split-bf16, fp32-grade)
    for (int blk = 0; blk < 2; blk++){
      const float* dww = b_dw_w + blk*H_*9;     const float* dwb = b_dw_b + blk*H_;
      const float* lnw = b_ln_w + blk*H_;       const float* lnb = b_ln_b + blk*H_;
      const float* p1w = b_pw1_w + blk*HID_*H_; const float* p1b = b_pw1_b + blk*HID_;
      const float* gg  = b_grn_g + blk*HID_;    const float* gb  = b_grn_b + blk*HID_;
      const float* p2w = b_pw2_w + blk*H_*HID_; const float* p2b = b_pw2_b + blk*H_;
      dwconv_ln_wave<<<(int)(Mc/16), 256, 0, stream>>>(h_c, dww, dwb, lnw, lnb, yln_c);
      gemm_mfma<1><<<dim3(gmx, 2), 256, 0, stream>>>(yln_c, p1w, p1b,
                                                     y1_c, nullptr, nullptr, gpart, HID_, H_);
      grn_combine_kernel<<<Bc, 384, 0, stream>>>(gpart, gg, scaleB);
      gemm_mfma<2><<<dim3(gmx, 1), 256, 0, stream>>>(y1_c, p2w, p2b,
                                                     h_c, scaleB, gb, nullptr, H_, HID_);
    }
    // 3. output LN -> h_seq, save last-t rows
    out_ln_wave<<<(int)(Mc/4), 256, 0, stream>>>(h_c, out_ln_w, out_ln_b, yln_c, hlast, ch*Bc);
    // 4. fused Kalman projection GEMM (writes rp directly) + FMA-only scan
    gemm_t128<3><<<dim3(gmx, 1), 256, 0, stream>>>(yln_c, w_pad, b_pad,
                                                   rp_c, nullptr, nullptr, nullptr, 64, H_);
    kalman_scan_kernel<<<(Bc+3)/4, 64, 0, stream>>>(x_c, rp_c, xpost, ch*Bc, Bc);
  }
  // 5. GRU rollout v3 (proven): 128 blocks x 768 threads, BPB=2
  rollout_kernel<<<B_/BPB, RT_, 0, stream>>>(hlast, xpost, wT1, roll_in_b, wPack,
                                             gru_bih, gru_bhh, roll_ln_w, roll_ln_b,
                                             fc_rp_r_w, fc_rp_r_b, out);
  (void)in_sizes; (void)n_in; (void)out_size; (void)ws_size;
}

// Round 10
// 1820.972 us; speedup vs baseline: 1.4004x; 1.0849x over previous
//
#include <hip/hip_runtime.h>
#include <cstdint>
#include <cstddef>

#define B_    256
#define Q_    512
#define D_    32
#define H_    192
#define HID_  384
#define INCH_ 96
#define M_    (B_*Q_)    // 131072
#define WOUT_ 64
#define BPB   2          // batches per rollout block
#define RT_   768        // rollout threads: 4 quarters x 192, 12 waves
#define PI_F  3.14159265358979323846f
#define LDS_S 40         // padded LDS row stride in shorts (32 bf16 + 8 pad)

typedef unsigned int uint_t;
typedef __attribute__((ext_vector_type(8))) short short8v;   // 8 bf16 = 4 VGPR
typedef __attribute__((ext_vector_type(4))) float floatx4;

__device__ __forceinline__ float sigm(float x){ return 1.f/(1.f+expf(-x)); }
__device__ __forceinline__ float gelu_exact(float x){ return 0.5f*x*(1.f+erff(x*0.7071067811865475f)); }
__device__ __forceinline__ float4 f4sub(float4 a, float4 b){
  return make_float4(a.x-b.x, a.y-b.y, a.z-b.z, a.w-b.w);
}

// round-to-nearest-even fp32 -> bf16 hi/lo split: v ~= hi + lo with ~2^-17 rel error
__device__ __forceinline__ void f2bf2(float v, unsigned short& h, unsigned short& l){
  unsigned u = __float_as_uint(v);
  unsigned rh = u + 0x7FFFu + ((u>>16)&1u);
  h = (unsigned short)(rh>>16);
  float fh = __uint_as_float(((unsigned)h)<<16);
  float lo = v - fh;
  unsigned ul = __float_as_uint(lo);
  unsigned rl = ul + 0x7FFFu + ((ul>>16)&1u);
  l = (unsigned short)(rl>>16);
}

#define MFMA_BF16(a,b,c) __builtin_amdgcn_mfma_f32_16x16x32_bf16((a),(b),(c),0,0,0)

// ---------------- on-the-fly features: [x, dy, ddy] column chunk ----------------
__device__ __forceinline__ float4 feats_load(const float* __restrict__ x, int bt, int c){
  const int t = bt & 511;
  const int seg = c >> 5, d = c & 31;
  const float* xr = x + (size_t)bt*D_ + d;
  float4 x0 = *(const float4*)xr;
  if (seg == 0) return x0;
  if (t == 0) return make_float4(0.f,0.f,0.f,0.f);
  float4 x1 = *(const float4*)(xr - D_);
  float4 dy = f4sub(x0, x1);
  if (seg == 1) return dy;
  if (t == 1) return dy;                 // dym1 = 0 -> ddy = dy
  float4 x2 = *(const float4*)(xr - 2*D_);
  float4 dym1 = f4sub(x1, x2);
  return f4sub(dy, dym1);
}

// ---------------- one-time: split pw1/pw2 weights into bf16 hi/lo arrays ----------------
__global__ void prep_wbf_kernel(const float* __restrict__ w1, const float* __restrict__ w2,
                                unsigned short* __restrict__ w1h, unsigned short* __restrict__ w1l,
                                unsigned short* __restrict__ w2h, unsigned short* __restrict__ w2l)
{
  int idx = blockIdx.x*256 + threadIdx.x;
  const int n1 = 2*HID_*H_;   // pw1: 2 blocks x [384][192]
  if (idx < n1){
    unsigned short h,l; f2bf2(w1[idx],h,l);
    w1h[idx]=h; w1l[idx]=l;
    return;
  }
  idx -= n1;
  if (idx < 2*H_*HID_){       // pw2: 2 blocks x [192][384]
    unsigned short h,l; f2bf2(w2[idx],h,l);
    w2h[idx]=h; w2l[idx]=l;
  }
}

// ---------------- MFMA split-bf16 GEMM: 128x192 tile, BK=32, 4 waves ----------------
// MODE 1 (pw1): A = packed (hi|lo) uint from dwconv; out = gelu(acc+bias), + GRN partials
// MODE 2 (pw2): A = fp32 with affine (scale/grnb), runtime split; C += acc+bias
// Weights pre-split (Wh/Wl) -> B-staging is pure copy. Bit-identical to R9 results.
template<int MODE>
__global__ __launch_bounds__(256,2) void gemm_mfma(
    const float* __restrict__ Af, const unsigned* __restrict__ Ap,
    const unsigned short* __restrict__ Wh, const unsigned short* __restrict__ Wl,
    const float* __restrict__ bias,
    float* __restrict__ Cf,
    const float* __restrict__ scale, const float* __restrict__ grnb,
    float* __restrict__ gpart,
    int N, int K)
{
  __shared__ __align__(16) unsigned short smem[25600];  // Ah[128][40] Al[128][40] Bh[192][40] Bl[192][40]
  unsigned short* Ah = smem;
  unsigned short* Al = smem + 128*LDS_S;
  unsigned short* Bh = smem + 256*LDS_S;
  unsigned short* Bl = smem + 256*LDS_S + 192*LDS_S;

  const int tid  = threadIdx.x;
  const int lane = tid & 63;
  const int wv   = tid >> 6;
  const int l15  = lane & 15;
  const int lg   = lane >> 4;
  const int bm = blockIdx.x*128, bn = blockIdx.y*192;

  floatx4 acc[2][12];
  #pragma unroll
  for (int i=0;i<2;i++)
    #pragma unroll
    for (int j=0;j<12;j++) acc[i][j] = (floatx4){0.f,0.f,0.f,0.f};

  const int arow = tid >> 1, akq = (tid & 1)*16;
  const float*    gA  = (MODE==2) ? (Af + (size_t)(bm+arow)*K) : nullptr;
  const unsigned* gAp = (MODE==1) ? (Ap + (size_t)(bm+arow)*K) : nullptr;
  const float* srow = (MODE==2) ? (scale + (size_t)(bm>>9)*HID_) : nullptr;

  for (int k0=0; k0<K; k0+=32){
    // ---- stage A ----
    if (MODE==1){
      #pragma unroll
      for (int i=0;i<4;i++){
        uint4 u = *(const uint4*)(gAp + k0 + akq + 4*i);
        unsigned h01 = (u.x & 0xFFFFu) | (u.y << 16);
        unsigned h23 = (u.z & 0xFFFFu) | (u.w << 16);
        unsigned l01 = (u.x >> 16) | (u.y & 0xFFFF0000u);
        unsigned l23 = (u.z >> 16) | (u.w & 0xFFFF0000u);
        uint2 uh; uh.x=h01; uh.y=h23;
        uint2 ul; ul.x=l01; ul.y=l23;
        *(uint2*)&Ah[arow*LDS_S + akq + 4*i] = uh;
        *(uint2*)&Al[arow*LDS_S + akq + 4*i] = ul;
      }
    } else {
      #pragma unroll
      for (int i=0;i<4;i++){
        float4 v = *(const float4*)(gA + k0 + akq + 4*i);
        int c = k0 + akq + 4*i;
        float4 sc = *(const float4*)(srow+c);
        float4 gb = *(const float4*)(grnb+c);
        v.x = v.x*sc.x+gb.x; v.y = v.y*sc.y+gb.y;
        v.z = v.z*sc.z+gb.z; v.w = v.w*sc.w+gb.w;
        unsigned short h0,h1,h2,h3,l0,l1,l2,l3;
        f2bf2(v.x,h0,l0); f2bf2(v.y,h1,l1); f2bf2(v.z,h2,l2); f2bf2(v.w,h3,l3);
        uint2 uh; uh.x = (unsigned)h0 | ((unsigned)h1<<16); uh.y = (unsigned)h2 | ((unsigned)h3<<16);
        uint2 ul; ul.x = (unsigned)l0 | ((unsigned)l1<<16); ul.y = (unsigned)l2 | ((unsigned)l3<<16);
        *(uint2*)&Ah[arow*LDS_S + akq + 4*i] = uh;
        *(uint2*)&Al[arow*LDS_S + akq + 4*i] = ul;
      }
    }
    // ---- stage B: pure copy from pre-split hi/lo ----
    for (int idx = tid; idx < 384; idx += 256){
      int br = idx >> 1, bkq = (idx & 1)*16;
      const unsigned short* gh = Wh + (size_t)(bn+br)*K + k0 + bkq;
      const unsigned short* gl = Wl + (size_t)(bn+br)*K + k0 + bkq;
      uint4 vh0 = *(const uint4*)(gh);
      uint4 vh1 = *(const uint4*)(gh+8);
      uint4 vl0 = *(const uint4*)(gl);
      uint4 vl1 = *(const uint4*)(gl+8);
      *(uint4*)&Bh[br*LDS_S + bkq]     = vh0;
      *(uint4*)&Bh[br*LDS_S + bkq + 8] = vh1;
      *(uint4*)&Bl[br*LDS_S + bkq]     = vl0;
      *(uint4*)&Bl[br*LDS_S + bkq + 8] = vl1;
    }
    __syncthreads();

    // ---- MFMA: one 16x16x32 k-tile per step ----
    const int a0off = (wv*32 + l15)*LDS_S + 8*lg;
    const int a1off = a0off + 16*LDS_S;
    short8v ah0 = *(const short8v*)&Ah[a0off];
    short8v al0 = *(const short8v*)&Al[a0off];
    short8v ah1 = *(const short8v*)&Ah[a1off];
    short8v al1 = *(const short8v*)&Al[a1off];
    #pragma unroll
    for (int ct=0; ct<12; ct++){
      const int boff = (ct*16 + l15)*LDS_S + 8*lg;
      short8v bh = *(const short8v*)&Bh[boff];
      short8v bl = *(const short8v*)&Bl[boff];
      acc[0][ct] = MFMA_BF16(ah0, bh, acc[0][ct]);
      acc[0][ct] = MFMA_BF16(ah0, bl, acc[0][ct]);
      acc[0][ct] = MFMA_BF16(al0, bh, acc[0][ct]);
      acc[1][ct] = MFMA_BF16(ah1, bh, acc[1][ct]);
      acc[1][ct] = MFMA_BF16(ah1, bl, acc[1][ct]);
      acc[1][ct] = MFMA_BF16(al1, bh, acc[1][ct]);
    }
    __syncthreads();
  }

  // ---- epilogue ----
  if (MODE==1){
    float* gq = (float*)smem;   // reuse: [192 cols][16 slots]
    #pragma unroll
    for (int ct=0; ct<12; ct++){
      const int col = bn + ct*16 + l15;
      const float b = bias[col];
      float qc = 0.f;
      #pragma unroll
      for (int rt=0; rt<2; rt++){
        const int rbase = bm + wv*32 + rt*16 + lg*4;
        #pragma unroll
        for (int r=0;r<4;r++){
          float v = gelu_exact(acc[rt][ct][r] + b);
          Cf[(size_t)(rbase+r)*N + col] = v;
          qc += v*v;
        }
      }
      gq[(ct*16+l15)*16 + (wv*4+lg)] = qc;
    }
    __syncthreads();
    if (tid < 192){
      float s = 0.f;
      #pragma unroll
      for (int j=0;j<16;j++) s += gq[tid*16+j];
      const int slot = (bm>>7)&3, b = bm>>9;
      gpart[((size_t)(b*4+slot))*HID_ + bn + tid] = s;
    }
  } else {
    #pragma unroll
    for (int ct=0; ct<12; ct++){
      const int col = bn + ct*16 + l15;
      const float b = bias[col];
      #pragma unroll
      for (int rt=0; rt<2; rt++){
        const int rbase = bm + wv*32 + rt*16 + lg*4;
        #pragma unroll
        for (int r=0;r<4;r++){
          size_t off = (size_t)(rbase+r)*N + col;
          Cf[off] = Cf[off] + acc[rt][ct][r] + b;
        }
      }
    }
  }
}

// ---------------- input GEMM: fused feature synthesis, 128x192 fp32 tile (N=192, K=96) ----------------
__global__ __launch_bounds__(256,2) void gemm_inp_w192(
    const float* __restrict__ x,
    const float* __restrict__ W,  const float* __restrict__ bias,
    float* __restrict__ Cf)
{
  __shared__ float smem[16*128 + 16*192];
  float* AsB = smem;
  float* BsB = smem + 16*128;
  const int tid = threadIdx.x;
  const int bm = blockIdx.x*128;
  const int tx = tid & 15, ty = tid >> 4;
  const int arow = tid >> 1, ak = (tid & 1)*4;
  const int br = tid >> 2,  bk = (tid & 3)*4;
  const int K = INCH_, N = H_;

  float acc[8][12];
  #pragma unroll
  for (int i=0;i<8;i++)
    #pragma unroll
    for (int j=0;j<12;j++) acc[i][j]=0.f;

  const float* gB0 = W + (size_t)(br)*K;
  const float* gB1 = W + (size_t)(br+64)*K;
  const float* gB2 = W + (size_t)(br+128)*K;

  for (int k0=0;k0<K;k0+=16){
    float4 va0 = feats_load(x, bm+arow, k0+ak);
    float4 va1 = feats_load(x, bm+arow, k0+ak+8);
    float4 vb0 = *(const float4*)(gB0 + k0 + bk);
    float4 vb1 = *(const float4*)(gB1 + k0 + bk);
    float4 vb2 = *(const float4*)(gB2 + k0 + bk);
    AsB[(ak+0)*128+arow]=va0.x; AsB[(ak+1)*128+arow]=va0.y; AsB[(ak+2)*128+arow]=va0.z; AsB[(ak+3)*128+arow]=va0.w;
    AsB[(ak+8)*128+arow]=va1.x; AsB[(ak+9)*128+arow]=va1.y; AsB[(ak+10)*128+arow]=va1.z; AsB[(ak+11)*128+arow]=va1.w;
    BsB[(bk+0)*192+br]=vb0.x; BsB[(bk+1)*192+br]=vb0.y; BsB[(bk+2)*192+br]=vb0.z; BsB[(bk+3)*192+br]=vb0.w;
    BsB[(bk+0)*192+br+64]=vb1.x; BsB[(bk+1)*192+br+64]=vb1.y; BsB[(bk+2)*192+br+64]=vb1.z; BsB[(bk+3)*192+br+64]=vb1.w;
    BsB[(bk+0)*192+br+128]=vb2.x; BsB[(bk+1)*192+br+128]=vb2.y; BsB[(bk+2)*192+br+128]=vb2.z; BsB[(bk+3)*192+br+128]=vb2.w;
    __syncthreads();
    #pragma unroll
    for (int kk=0;kk<16;kk++){
      float4 a0 = *(const float4*)&AsB[kk*128 + ty*8];
      float4 a1 = *(const float4*)&AsB[kk*128 + ty*8 + 4];
      float4 b0 = *(const float4*)&BsB[kk*192 + tx*12];
      float4 b1 = *(const float4*)&BsB[kk*192 + tx*12 + 4];
      float4 b2 = *(const float4*)&BsB[kk*192 + tx*12 + 8];
      float ar[8] = {a0.x,a0.y,a0.z,a0.w,a1.x,a1.y,a1.z,a1.w};
      #pragma unroll
      for (int i=0;i<8;i++){
        acc[i][0] += ar[i]*b0.x; acc[i][1] += ar[i]*b0.y; acc[i][2] += ar[i]*b0.z; acc[i][3] += ar[i]*b0.w;
        acc[i][4] += ar[i]*b1.x; acc[i][5] += ar[i]*b1.y; acc[i][6] += ar[i]*b1.z; acc[i][7] += ar[i]*b1.w;
        acc[i][8] += ar[i]*b2.x; acc[i][9] += ar[i]*b2.y; acc[i][10]+= ar[i]*b2.z; acc[i][11]+= ar[i]*b2.w;
      }
    }
    __syncthreads();
  }

  const int o0 = tx*12;
  float4 bb0 = *(const float4*)(bias + o0);
  float4 bb1 = *(const float4*)(bias + o0 + 4);
  float4 bb2 = *(const float4*)(bias + o0 + 8);
  #pragma unroll
  for (int i=0;i<8;i++){
    int m = bm + ty*8 + i;
    float* crow = Cf + (size_t)m*N + o0;
    float4 v0, v1, v2;
    v0.x=acc[i][0]+bb0.x; v0.y=acc[i][1]+bb0.y; v0.z=acc[i][2]+bb0.z; v0.w=acc[i][3]+bb0.w;
    v1.x=acc[i][4]+bb1.x; v1.y=acc[i][5]+bb1.y; v1.z=acc[i][6]+bb1.z; v1.w=acc[i][7]+bb1.w;
    v2.x=acc[i][8]+bb2.x; v2.y=acc[i][9]+bb2.y; v2.z=acc[i][10]+bb2.z; v2.w=acc[i][11]+bb2.w;
    *(float4*)(crow+0) = v0; *(float4*)(crow+4) = v1; *(float4*)(crow+8) = v2;
  }
}

// ---------------- 128x64x16 fp32 GEMM (kept only for MODE 3: Kalman projection, N=64) ----------------
template<int MODE>
__global__ __launch_bounds__(256,4) void gemm_t128(
    const float* __restrict__ Af,
    const float* __restrict__ W,  const float* __restrict__ bias,
    float* __restrict__ Cf,
    const float* __restrict__ scale, const float* __restrict__ grnb,
    float* __restrict__ gpart,
    int N, int K)
{
  __shared__ float As[16][128];
  __shared__ float Bs[16][64];
  const int tid = threadIdx.x;
  const int bm = blockIdx.x*128, bn = blockIdx.y*64;
  const int tx = tid & 15, ty = tid >> 4;
  const int arow = tid >> 1, ak = (tid & 1)*4;
  const int brow = tid >> 2, bk = (tid & 3)*4;

  float acc[8][4];
  #pragma unroll
  for (int i=0;i<8;i++)
    #pragma unroll
    for (int j=0;j<4;j++) acc[i][j]=0.f;

  const float* gA = Af + (size_t)(bm+arow)*K;
  const float* gB = W  + (size_t)(bn+brow)*K;

  for (int k0=0;k0<K;k0+=16){
    float4 va0 = *(const float4*)(gA + k0 + ak);
    float4 va1 = *(const float4*)(gA + k0 + ak + 8);
    float4 vb  = *(const float4*)(gB + k0 + bk);
    As[ak+0][arow]=va0.x; As[ak+1][arow]=va0.y; As[ak+2][arow]=va0.z; As[ak+3][arow]=va0.w;
    As[ak+8][arow]=va1.x; As[ak+9][arow]=va1.y; As[ak+10][arow]=va1.z; As[ak+11][arow]=va1.w;
    Bs[bk+0][brow]=vb.x; Bs[bk+1][brow]=vb.y; Bs[bk+2][brow]=vb.z; Bs[bk+3][brow]=vb.w;
    __syncthreads();
    #pragma unroll
    for (int kk=0;kk<16;kk++){
      float4 a0 = *(const float4*)&As[kk][ty*8];
      float4 a1 = *(const float4*)&As[kk][ty*8+4];
      float4 b  = *(const float4*)&Bs[kk][tx*4];
      float ar[8] = {a0.x,a0.y,a0.z,a0.w,a1.x,a1.y,a1.z,a1.w};
      #pragma unroll
      for (int i=0;i<8;i++){
        acc[i][0] += ar[i]*b.x; acc[i][1] += ar[i]*b.y;
        acc[i][2] += ar[i]*b.z; acc[i][3] += ar[i]*b.w;
      }
    }
    __syncthreads();
  }

  const int o0 = bn + tx*4;
  float4 b0 = *(const float4*)(bias + o0);

  if (MODE==3){
    #pragma unroll
    for (int i=0;i<8;i++){
      int m = bm + ty*8 + i;
      float* ob = Cf + (size_t)m*34;
      float vx = acc[i][0]+b0.x, vy = acc[i][1]+b0.y;
      float vz = acc[i][2]+b0.z, vw = acc[i][3]+b0.w;
      if (o0 == 0){
        float rho = 1.25f*sigm(vx);
        float phi = PI_F*tanhf(vy);
        ob[0] = rho*cosf(phi); ob[1] = rho*sinf(phi);
        ob[2] = sigm(vz); ob[3] = sigm(vw);
      } else if (o0 <= 28){
        ob[o0+0]=sigm(vx); ob[o0+1]=sigm(vy); ob[o0+2]=sigm(vz); ob[o0+3]=sigm(vw);
      } else if (o0 == 32){
        ob[32]=sigm(vx); ob[33]=sigm(vy);
      }
    }
    return;
  }
  (void)gpart; (void)scale; (void)grnb;
}

// ---------------- depthwise conv + wave-local LN; emits packed (hi|lo) bf16 uint ----------------
// f2bf2 applied to the identical fp32 LN output value pw1 would have split -> bit-identical.
__global__ __launch_bounds__(256) void dwconv_ln_wave(
  const float* __restrict__ h, const float* __restrict__ dww, const float* __restrict__ dwb,
  const float* __restrict__ lnw, const float* __restrict__ lnb, unsigned* __restrict__ yln)
{
  __shared__ float sh[24][192];
  const int tid  = threadIdx.x;
  const int lane = tid & 63;
  const int wv   = tid >> 6;
  const int t0 = (blockIdx.x & 31) * 16;
  const size_t base = (size_t)(blockIdx.x >> 5) * Q_ * H_;
  #pragma unroll
  for (int i = tid; i < 24*192; i += 256){
    int r = i / 192, c = i - r*192;
    int tt = t0 - 4 + r; tt = tt<0?0:(tt>511?511:tt);
    sh[r][c] = h[base + (size_t)tt*H_ + c];
  }
  const int c0 = lane, c1 = lane+64, c2 = lane+128;
  float w0[9], w1[9], w2[9];
  #pragma unroll
  for (int k=0;k<9;k++){ w0[k]=dww[c0*9+k]; w1[k]=dww[c1*9+k]; w2[k]=dww[c2*9+k]; }
  const float db0=dwb[c0], db1=dwb[c1], db2=dwb[c2];
  const float lw0=lnw[c0], lw1=lnw[c1], lw2=lnw[c2];
  const float lb0=lnb[c0], lb1=lnb[c1], lb2=lnb[c2];
  __syncthreads();
  for (int it=0; it<4; it++){
    const int i = it*4 + wv;
    float a0=db0, a1=db1, a2=db2;
    #pragma unroll
    for (int k=0;k<9;k++){
      a0 += w0[k]*sh[i+k][c0];
      a1 += w1[k]*sh[i+k][c1];
      a2 += w2[k]*sh[i+k][c2];
    }
    float s = a0+a1+a2;
    float qq = a0*a0 + a1*a1 + a2*a2;
    #pragma unroll
    for (int off=32; off>0; off>>=1){ s += __shfl_down(s,off); qq += __shfl_down(qq,off); }
    s = __shfl(s, 0); qq = __shfl(qq, 0);
    float mean = s*(1.f/H_);
    float var  = qq*(1.f/H_) - mean*mean;
    float r = rsqrtf(var + 1e-5f);
    unsigned* ob = yln + base + (size_t)(t0+i)*H_;
    unsigned short hh,ll;
    f2bf2((a0-mean)*r*lw0 + lb0, hh, ll); ob[c0] = (unsigned)hh | ((unsigned)ll<<16);
    f2bf2((a1-mean)*r*lw1 + lb1, hh, ll); ob[c1] = (unsigned)hh | ((unsigned)ll<<16);
    f2bf2((a2-mean)*r*lw2 + lb2, hh, ll); ob[c2] = (unsigned)hh | ((unsigned)ll<<16);
  }
}

// ---------------- output LayerNorm, wave-local (4 rows/block, no LDS, no barriers) ----------------
__global__ __launch_bounds__(256) void out_ln_wave(
  const float* __restrict__ h, const float* __restrict__ lnw, const float* __restrict__ lnb,
  float* __restrict__ o, float* __restrict__ hlast, int b0)
{
  const int tid  = threadIdx.x;
  const int lane = tid & 63;
  const int wv   = tid >> 6;
  const int bt = blockIdx.x*4 + wv;
  const float* hr = h + (size_t)bt*H_;
  float v0 = hr[lane], v1 = hr[lane+64], v2 = hr[lane+128];
  float s = v0+v1+v2;
  float qq = v0*v0 + v1*v1 + v2*v2;
  #pragma unroll
  for (int off=32; off>0; off>>=1){ s += __shfl_down(s,off); qq += __shfl_down(qq,off); }
  s = __shfl(s, 0); qq = __shfl(qq, 0);
  float mean = s*(1.f/H_);
  float var  = qq*(1.f/H_) - mean*mean;
  float r = rsqrtf(var + 1e-5f);
  const float r0 = (v0-mean)*r*lnw[lane]     + lnb[lane];
  const float r1 = (v1-mean)*r*lnw[lane+64]  + lnb[lane+64];
  const float r2 = (v2-mean)*r*lnw[lane+128] + lnb[lane+128];
  float* orow = o + (size_t)bt*H_;
  orow[lane] = r0; orow[lane+64] = r1; orow[lane+128] = r2;
  if ((bt & 511) == 511){
    float* hl = hlast + (size_t)(b0 + (bt>>9))*H_;
    hl[lane] = r0; hl[lane+64] = r1; hl[lane+128] = r2;
  }
}

// ---------------- GRN combine: 4 slot partials -> scale ----------------
__global__ __launch_bounds__(384) void grn_combine_kernel(
  const float* __restrict__ gpart, const float* __restrict__ grn_g, float* __restrict__ scale)
{
  __shared__ float r[384];
  const int c = threadIdx.x;
  const int b = blockIdx.x;
  const float* p = gpart + (size_t)b*4*HID_;
  float s = ((p[c] + p[HID_+c]) + p[2*HID_+c]) + p[3*HID_+c];
  float gx = sqrtf(s);
  r[c] = gx;
  __syncthreads();
  if (c < 64){
    float v = r[c]+r[c+64]+r[c+128]+r[c+192]+r[c+256]+r[c+320];
    #pragma unroll
    for (int off=32; off>0; off>>=1) v += __shfl_down(v,off);
    if (c==0) r[0]=v;
  }
  __syncthreads();
  float mean = r[0]*(1.f/HID_);
  scale[(size_t)b*HID_ + c] = 1.f + grn_g[c]*gx/(mean + 1e-6f);
}

// ---------------- pack fc_rp / fc_gain into padded (64,192) W ----------------
__global__ void pack_w_kernel(const float* __restrict__ frw, const float* __restrict__ frb,
                              const float* __restrict__ fgw, const float* __restrict__ fgb,
                              float* __restrict__ w_pad, float* __restrict__ b_pad)
{
  int idx = blockIdx.x*256 + threadIdx.x;
  if (idx >= 64*192) return;
  int o = idx / 192, k = idx % 192;
  float v = 0.f;
  if (o < 2) v = frw[o*192+k]; else if (o < 34) v = fgw[(o-2)*192+k];
  w_pad[idx] = v;
  if (k == 0){
    float bv = 0.f;
    if (o < 2) bv = frb[o]; else if (o < 34) bv = fgb[o-2];
    b_pad[o] = bv;
  }
}

// ---------------- sequential Kalman scan (FMA-only) ----------------
__global__ __launch_bounds__(64) void kalman_scan_kernel(
  const float* __restrict__ x_c, const float* __restrict__ rp, float* __restrict__ xpost,
  int b0, int Bc)
{
  const int lane = threadIdx.x;
  const int bl = blockIdx.x*4 + (lane>>4);
  if (bl >= Bc) return;
  const int m = lane & 15;
  const float* xb  = x_c + (size_t)bl*Q_*D_;
  const float* rpb = rp  + (size_t)bl*Q_*34;
  float re = xb[m], im = xb[16+m];
  for (int t=0;t<Q_;t++){
    const float* r = rpb + (size_t)t*34;
    float rc = r[0], rs = r[1];
    float g0 = r[2+m], g1 = r[18+m];
    float y0 = xb[(size_t)t*D_ + m], y1v = xb[(size_t)t*D_ + 16 + m];
    float pr  = rc*re - rs*im;
    float pim = rs*re + rc*im;
    re = pr  + g0*(y0  - pr);
    im = pim + g1*(y1v - pim);
  }
  xpost[(b0+bl)*D_ + m] = re;
  xpost[(b0+bl)*D_ + 16 + m] = im;
}

// ---------------- rollout weight prep: wT1[k][o] + de-padded k-pair pack [p][o][12] ----------------
__global__ void prep_rollout_kernel(const float* __restrict__ riw, const float* __restrict__ wih,
                                    const float* __restrict__ whh,
                                    float* __restrict__ wT1, float* __restrict__ wPack)
{
  int idx = blockIdx.x*256 + threadIdx.x;
  if (idx < 224*192){
    int o = idx % 192, k = idx / 192;
    wT1[idx] = riw[o*224 + k];
    return;
  }
  idx -= 224*192;
  if (idx < 192*192){
    int o = idx % 192, k = idx / 192;
    float* w = wPack + ((size_t)(k>>1)*192 + o)*12 + (k&1)*6;
    w[0] = wih[(0*192+o)*192 + k];
    w[1] = wih[(1*192+o)*192 + k];
    w[2] = wih[(2*192+o)*192 + k];
    w[3] = whh[(0*192+o)*192 + k];
    w[4] = whh[(1*192+o)*192 + k];
    w[5] = whh[(2*192+o)*192 + k];
  }
}

// ---------------- GRU rollout v3.1: de-padded weight stream (12 floats / k-pair, -25% bytes) ----------------
// Same k-ascending accumulation order as v3 -> bit-identical. L1-fill bound on the weight
// stream (R1/R2: step time tracks bytes/CU/step, invariant to BPB).
__global__ __launch_bounds__(RT_,3) void rollout_kernel(
  const float* __restrict__ hlast, const float* __restrict__ xpost,
  const float* __restrict__ wT1,  const float* __restrict__ rib_,
  const float* __restrict__ wPack,
  const float* __restrict__ bih,  const float* __restrict__ bhh,
  const float* __restrict__ lnw,  const float* __restrict__ lnb,
  const float* __restrict__ frw,  const float* __restrict__ frb,
  float* __restrict__ out)
{
  const int tid = threadIdx.x;
  const int q   = tid / 192;        // quarter 0..3 (wave-aligned: 192 = 3 waves)
  const int o   = tid - q*192;      // channel 0..191
  const int bb  = blockIdx.x*BPB;

  __shared__ float hT[192][2];      // h state, batch-major
  __shared__ float xT[192][2];      // x = tanh(W1 [h;c]), batch-major
  __shared__ float cT[32][2];       // curr (Kalman state), batch-major
  __shared__ float pA[4][2][192];   // phase-A partials [quarter][batch][o]
  __shared__ float pB[4][12][192];  // phase-B partials [quarter][batch*6+gate][o]
  __shared__ float rsum[2][3][4];   // [batch][wave][S1,S2,S3,S4]

  // ---- init state ----
  if (q < 2){
    hT[o][q] = hlast[(size_t)(bb+q)*H_ + o];
    if (o < 32) cT[o][q] = xpost[(bb+q)*D_ + o];
  }

  const float w_ln = lnw[o], b_ln = lnb[o];
  const float fr0  = frw[o], fr1  = frw[192+o];
  const float fb0 = frb[0],  fb1 = frb[1];
  const float bi0 = bih[o], bi1 = bih[192+o], bi2 = bih[384+o];
  const float bh0 = bhh[o], bh1 = bhh[192+o], bh2 = bhh[384+o];
  const float rib = rib_[o];
  const float u0 = w_ln*fr0, u1 = w_ln*fr1;      // for fused projection
  const float t0c = b_ln*fr0, t1c = b_ln*fr1;

  // ---- phase-A weights in registers (step-invariant) ----
  float wreg[56];
  if (q < 3){
    const int kb = 56*q;
    #pragma unroll
    for (int i=0;i<56;i++) wreg[i] = wT1[(kb+i)*192+o];
  } else {
    #pragma unroll
    for (int i=0;i<24;i++) wreg[i] = wT1[(168+i)*192+o];
    #pragma unroll
    for (int i=0;i<32;i++) wreg[24+i] = wT1[(192+i)*192+o];
  }

  // ---- one-time constants ----
  {
    float c0=u0, c1=u1, k0=t0c, k1=t1c;
    #pragma unroll
    for (int off=32; off>0; off>>=1){
      c0 += __shfl_down(c0,off); c1 += __shfl_down(c1,off);
      k0 += __shfl_down(k0,off); k1 += __shfl_down(k1,off);
    }
    if (q==0 && (o&63)==0){
      int w = o>>6;
      rsum[0][w][0]=c0; rsum[0][w][1]=c1; rsum[0][w][2]=k0; rsum[0][w][3]=k1;
    }
  }
  __syncthreads();
  const float C0 = rsum[0][0][0]+rsum[0][1][0]+rsum[0][2][0];
  const float C1 = rsum[0][0][1]+rsum[0][1][1]+rsum[0][2][1];
  const float K0 = rsum[0][0][2]+rsum[0][1][2]+rsum[0][2][2] + fb0;
  const float K1 = rsum[0][0][3]+rsum[0][1][3]+rsum[0][2][3] + fb1;

  for (int s=0; s<WOUT_; s++){
    // ---- phase A: partial x = W1 @ [h;c], K=224 split 4-way, weights in regs ----
    float a0=0.f, a1=0.f;
    if (q < 3){
      const int kb = 56*q;
      #pragma unroll
      for (int i=0;i<56;i++){
        float2 h2 = *(const float2*)&hT[kb+i][0];
        a0 += wreg[i]*h2.x; a1 += wreg[i]*h2.y;
      }
    } else {
      #pragma unroll
      for (int i=0;i<24;i++){
        float2 h2 = *(const float2*)&hT[168+i][0];
        a0 += wreg[i]*h2.x; a1 += wreg[i]*h2.y;
      }
      #pragma unroll
      for (int i=0;i<32;i++){
        float2 c2 = *(const float2*)&cT[i][0];
        a0 += wreg[24+i]*c2.x; a1 += wreg[24+i]*c2.y;
      }
    }
    pA[q][0][o]=a0; pA[q][1][o]=a1;
    __syncthreads();

    // ---- x combine: quarter j (<2) owns batch j ----
    if (q < 2){
      xT[o][q] = tanhf(rib + pA[0][q][o] + pA[1][q][o] + pA[2][q][o] + pA[3][q][o]);
    }
    __syncthreads();

    // ---- phase B: partial gates, K=192 split 4-way (24 k-pairs each) ----
    float accx[2][3] = {{0.f,0.f,0.f},{0.f,0.f,0.f}};
    float acch[2][3] = {{0.f,0.f,0.f},{0.f,0.f,0.f}};
    {
      const int pb = 24*q;
      #pragma unroll 2
      for (int i=0;i<24;i++){
        const int p = pb+i;
        const float4* wp = (const float4*)(wPack + ((size_t)p*192 + o)*12);
        const float4 qa = wp[0];   // i0e i1e i2e h0e
        const float4 qb = wp[1];   // h1e h2e i0o i1o
        const float4 qc = wp[2];   // i2o h0o h1o h2o
        const float4 xx = *(const float4*)&xT[2*p][0];  // (b0,b1)@k_even , (b0,b1)@k_odd
        const float4 hh = *(const float4*)&hT[2*p][0];
        // even k
        accx[0][0] += qa.x*xx.x; accx[0][1] += qa.y*xx.x; accx[0][2] += qa.z*xx.x;
        accx[1][0] += qa.x*xx.y; accx[1][1] += qa.y*xx.y; accx[1][2] += qa.z*xx.y;
        acch[0][0] += qa.w*hh.x; acch[0][1] += qb.x*hh.x; acch[0][2] += qb.y*hh.x;
        acch[1][0] += qa.w*hh.y; acch[1][1] += qb.x*hh.y; acch[1][2] += qb.y*hh.y;
        // odd k
        accx[0][0] += qb.z*xx.z; accx[0][1] += qb.w*xx.z; accx[0][2] += qc.x*xx.z;
        accx[1][0] += qb.z*xx.w; accx[1][1] += qb.w*xx.w; accx[1][2] += qc.x*xx.w;
        acch[0][0] += qc.y*hh.z; acch[0][1] += qc.z*hh.z; acch[0][2] += qc.w*hh.z;
        acch[1][0] += qc.y*hh.w; acch[1][1] += qc.z*hh.w; acch[1][2] += qc.w*hh.w;
      }
    }
    #pragma unroll
    for (int j=0;j<2;j++){
      #pragma unroll
      for (int g=0;g<3;g++){
        pB[q][j*6+g][o]   = accx[j][g];
        pB[q][j*6+3+g][o] = acch[j][g];
      }
    }
    __syncthreads();

    // ---- gate combine + fused 4-sum wave reduction (quarters 0/1 own batch q) ----
    float pre = 0.f;
    if (q < 2){
      const int g6 = q*6;
      float P0 = bi0 + pB[0][g6+0][o]+pB[1][g6+0][o]+pB[2][g6+0][o]+pB[3][g6+0][o];
      float P1 = bi1 + pB[0][g6+1][o]+pB[1][g6+1][o]+pB[2][g6+1][o]+pB[3][g6+1][o];
      float P2 = bi2 + pB[0][g6+2][o]+pB[1][g6+2][o]+pB[2][g6+2][o]+pB[3][g6+2][o];
      float Q0 = bh0 + pB[0][g6+3][o]+pB[1][g6+3][o]+pB[2][g6+3][o]+pB[3][g6+3][o];
      float Q1 = bh1 + pB[0][g6+4][o]+pB[1][g6+4][o]+pB[2][g6+4][o]+pB[3][g6+4][o];
      float Q2 = bh2 + pB[0][g6+5][o]+pB[1][g6+5][o]+pB[2][g6+5][o]+pB[3][g6+5][o];
      float rg = sigm(P0+Q0), zz = sigm(P1+Q1);
      float nn = tanhf(P2 + rg*Q2);
      pre = (1.f-zz)*nn + zz*hT[o][q];
      float s1 = pre, s2 = pre*pre, s3 = pre*u0, s4 = pre*u1;
      #pragma unroll
      for (int off=32; off>0; off>>=1){
        s1 += __shfl_down(s1,off); s2 += __shfl_down(s2,off);
        s3 += __shfl_down(s3,off); s4 += __shfl_down(s4,off);
      }
      if ((o&63)==0){
        int w = o>>6;
        rsum[q][w][0]=s1; rsum[q][w][1]=s2; rsum[q][w][2]=s3; rsum[q][w][3]=s4;
      }
    }
    __syncthreads();

    // ---- concurrent tail: LN update (q<2) || Kalman rotate (q>=2, o<16) ----
    if (q < 2){
      float S1 = rsum[q][0][0]+rsum[q][1][0]+rsum[q][2][0];
      float S2 = rsum[q][0][1]+rsum[q][1][1]+rsum[q][2][1];
      float mu  = S1*(1.f/192.f);
      float var = S2*(1.f/192.f) - mu*mu;
      float r = rsqrtf(var+1e-5f);
      hT[o][q] = (pre-mu)*r*w_ln + b_ln;
    } else if (o < 16){
      const int j = q-2;
      float S1 = rsum[j][0][0]+rsum[j][1][0]+rsum[j][2][0];
      float S2 = rsum[j][0][1]+rsum[j][1][1]+rsum[j][2][1];
      float S3 = rsum[j][0][2]+rsum[j][1][2]+rsum[j][2][2];
      float S4 = rsum[j][0][3]+rsum[j][1][3]+rsum[j][2][3];
      float mu  = S1*(1.f/192.f);
      float var = S2*(1.f/192.f) - mu*mu;
      float r = rsqrtf(var+1e-5f);
      float proj0 = r*(S3 - mu*C0) + K0;
      float proj1 = r*(S4 - mu*C1) + K1;
      float rho = 1.25f*sigm(proj0);
      float phi = PI_F*tanhf(proj1);
      float rc = rho*cosf(phi), rs = rho*sinf(phi);
      float re = cT[o][j], im = cT[o+16][j];
      float nre = rc*re - rs*im;
      float nim = rs*re + rc*im;
      cT[o][j] = nre; cT[o+16][j] = nim;
      float* ob = out + ((size_t)(bb+j)*WOUT_ + s)*D_;
      ob[o] = nre; ob[o+16] = nim;
    }
    __syncthreads();
  }
}

// ---------------- host launch ----------------
extern "C" void kernel_launch(void* const* d_in, const int* in_sizes, int n_in,
                              void* d_out, int out_size, void* d_ws, size_t ws_size,
                              hipStream_t stream)
{
  const float* x_in     = (const float*)d_in[0];
  const float* inp_w    = (const float*)d_in[1];
  const float* inp_b    = (const float*)d_in[2];
  const float* b_dw_w   = (const float*)d_in[3];
  const float* b_dw_b   = (const float*)d_in[4];
  const float* b_ln_w   = (const float*)d_in[5];
  const float* b_ln_b   = (const float*)d_in[6];
  const float* b_pw1_w  = (const float*)d_in[7];
  const float* b_pw1_b  = (const float*)d_in[8];
  const float* b_grn_g  = (const float*)d_in[9];
  const float* b_grn_b  = (const float*)d_in[10];
  const float* b_pw2_w  = (const float*)d_in[11];
  const float* b_pw2_b  = (const float*)d_in[12];
  const float* out_ln_w = (const float*)d_in[13];
  const float* out_ln_b = (const float*)d_in[14];
  const float* fc_rp_w  = (const float*)d_in[15];
  const float* fc_rp_b  = (const float*)d_in[16];
  const float* fc_gain_w= (const float*)d_in[17];
  const float* fc_gain_b= (const float*)d_in[18];
  const float* roll_in_w= (const float*)d_in[19];
  const float* roll_in_b= (const float*)d_in[20];
  const float* gru_wih  = (const float*)d_in[21];
  const float* gru_whh  = (const float*)d_in[22];
  const float* gru_bih  = (const float*)d_in[23];
  const float* gru_bhh  = (const float*)d_in[24];
  const float* roll_ln_w= (const float*)d_in[25];
  const float* roll_ln_b= (const float*)d_in[26];
  const float* fc_rp_r_w= (const float*)d_in[27];
  const float* fc_rp_r_b= (const float*)d_in[28];
  float* out = (float*)d_out;

  // ---- adaptive chunking ----
  // fixed tail: prev 899136 + wbf 294912 = 1194048 ; + margin
  const size_t SMAL_FLOATS = 1194048 + 4096;
  size_t ws_floats = ws_size / 4;
  int nchunk = 256;
  const int cand[9] = {1,2,4,8,16,32,64,128,256};
  for (int ci=0; ci<9; ci++){
    size_t Mc_try = (size_t)M_ / cand[ci];
    if (Mc_try*768 + SMAL_FLOATS <= ws_floats){ nchunk = cand[ci]; break; }
  }
  const int    Bc = B_ / nchunk;
  const size_t Mc = (size_t)Bc * Q_;

  float* ws    = (float*)d_ws;
  float* h_c   = ws;
  float* yln_c = h_c   + Mc*192;
  float* mid_c = yln_c + Mc*192;
  float* smal  = mid_c + Mc*384;

  float* y1_c    = mid_c;
  float* rp_c    = mid_c;                // Mc*34 (y1 dead by then)

  float* scaleB = smal;                  // Bc*384 (reserve 98304)
  float* w_pad  = smal + 98304;          // 64*192
  float* b_pad  = w_pad + 12288;         // 64
  float* xpost  = b_pad + 64;            // B_*32
  float* hlast  = xpost + 8192;          // B_*192
  float* wT1    = hlast + 49152;         // 224*192
  float* wPack  = wT1 + 43008;           // 96*192*12 (reserve 294912)
  float* gpart  = wPack + 294912;        // 4*Bc*384 (reserve 393216)
  float* wbf    = gpart + 393216;        // 4 x 147456 ushorts = 294912 floats
  unsigned short* w1h = (unsigned short*)wbf;
  unsigned short* w1l = w1h + 2*HID_*H_;
  unsigned short* w2h = w1l + 2*HID_*H_;
  unsigned short* w2l = w2h + 2*H_*HID_;

  // one-time weight prep
  pack_w_kernel<<<(64*192+255)/256, 256, 0, stream>>>(fc_rp_w, fc_rp_b, fc_gain_w, fc_gain_b, w_pad, b_pad);
  prep_rollout_kernel<<<(224*192+192*192+255)/256, 256, 0, stream>>>(roll_in_w, gru_wih, gru_whh, wT1, wPack);
  prep_wbf_kernel<<<(4*HID_*H_+255)/256, 256, 0, stream>>>(b_pw1_w, b_pw2_w, w1h, w1l, w2h, w2l);

  const int gmx = (int)(Mc/128);
  for (int ch=0; ch<nchunk; ch++){
    const float* x_c = x_in + (size_t)ch*Mc*D_;
    // 1. fused features + input projection (fp32, small)
    gemm_inp_w192<<<dim3(gmx, 1), 256, 0, stream>>>(x_c, inp_w, inp_b, h_c);
    // 2. ConvNeXt blocks — pw1/pw2 on matrix cores; weights pre-split, yln pre-split
    for (int blk = 0; blk < 2; blk++){
      const float* dww = b_dw_w + blk*H_*9;     const float* dwb = b_dw_b + blk*H_;
      const float* lnw = b_ln_w + blk*H_;       const float* lnb = b_ln_b + blk*H_;
      const float* p1b = b_pw1_b + blk*HID_;
      const float* gg  = b_grn_g + blk*HID_;    const float* gb  = b_grn_b + blk*HID_;
      const float* p2b = b_pw2_b + blk*H_;
      dwconv_ln_wave<<<(int)(Mc/16), 256, 0, stream>>>(h_c, dww, dwb, lnw, lnb, (unsigned*)yln_c);
      gemm_mfma<1><<<dim3(gmx, 2), 256, 0, stream>>>(nullptr, (const unsigned*)yln_c,
                                                     w1h + blk*HID_*H_, w1l + blk*HID_*H_, p1b,
                                                     y1_c, nullptr, nullptr, gpart, HID_, H_);
      grn_combine_kernel<<<Bc, 384, 0, stream>>>(gpart, gg, scaleB);
      gemm_mfma<2><<<dim3(gmx, 1), 256, 0, stream>>>(y1_c, nullptr,
                                                     w2h + blk*H_*HID_, w2l + blk*H_*HID_, p2b,
                                                     h_c, scaleB, gb, nullptr, H_, HID_);
    }
    // 3. output LN -> h_seq, save last-t rows
    out_ln_wave<<<(int)(Mc/4), 256, 0, stream>>>(h_c, out_ln_w, out_ln_b, yln_c, hlast, ch*Bc);
    // 4. fused Kalman projection GEMM (writes rp directly) + FMA-only scan
    gemm_t128<3><<<dim3(gmx, 1), 256, 0, stream>>>(yln_c, w_pad, b_pad,
                                                   rp_c, nullptr, nullptr, nullptr, 64, H_);
    kalman_scan_kernel<<<(Bc+3)/4, 64, 0, stream>>>(x_c, rp_c, xpost, ch*Bc, Bc);
  }
  // 5. GRU rollout v3.1: 128 blocks x 768 threads, de-padded weight stream
  rollout_kernel<<<B_/BPB, RT_, 0, stream>>>(hlast, xpost, wT1, roll_in_b, wPack,
                                             gru_bih, gru_bhh, roll_ln_w, roll_ln_b,
                                             fc_rp_r_w, fc_rp_r_b, out);
  (void)in_sizes; (void)n_in; (void)out_size; (void)ws_size;
}